// Round 2
// baseline (754.791 us; speedup 1.0000x reference)
//
#include <hip/hip_runtime.h>
#include <hip/hip_bf16.h>

#define N_NODES 100000
#define NE      1600000
#define D_IN    128
#define D_H     128
#define D_OUT   64

// ---------------------------------------------------------------------------
// JAX threefry2x32, partitionable path (default since JAX 0.4.36).
// key = (0, 42). For element f: counter = (hi=0, lo=f),
// bits = out0 ^ out1. keep <=> top bit == 0  (uniform<0.5).
// ---------------------------------------------------------------------------
__device__ __forceinline__ unsigned tf_rotl(unsigned x, int d) {
    return (x << d) | (x >> (32 - d));
}

__device__ __forceinline__ unsigned tf_word(unsigned f) {
    const unsigned ks0 = 0u;
    const unsigned ks1 = 42u;
    const unsigned ks2 = 0x1BD11BDAu ^ 0u ^ 42u;
    unsigned x0 = 0u + ks0;      // counts_hi + ks[0]
    unsigned x1 = f + ks1;       // counts_lo + ks[1]
#define TF_RND(r) { x0 += x1; x1 = tf_rotl(x1, r); x1 ^= x0; }
    TF_RND(13) TF_RND(15) TF_RND(26) TF_RND(6)
    x0 += ks1; x1 += ks2 + 1u;
    TF_RND(17) TF_RND(29) TF_RND(16) TF_RND(24)
    x0 += ks2; x1 += ks0 + 2u;
    TF_RND(13) TF_RND(15) TF_RND(26) TF_RND(6)
    x0 += ks0; x1 += ks1 + 3u;
    TF_RND(17) TF_RND(29) TF_RND(16) TF_RND(24)
    x0 += ks1; x1 += ks2 + 4u;
    TF_RND(13) TF_RND(15) TF_RND(26) TF_RND(6)
    x0 += ks2; x1 += ks0 + 5u;
#undef TF_RND
    return x0 ^ x1;
}

// ---------------------------------------------------------------------------
// edge_index dtype probe: int64 data => odd 32-bit words of row0 are all 0.
// int32 data => odd words are random node ids (nonzero w.h.p.).
// flag = 1 if int64, 0 if int32. Deterministic.
// ---------------------------------------------------------------------------
__global__ void k_detect(const int* __restrict__ ei, int* __restrict__ flag) {
    __shared__ int nz;
    if (threadIdx.x == 0) nz = 0;
    __syncthreads();
    for (int i = threadIdx.x; i < 1024; i += blockDim.x)
        if (ei[2 * i + 1] != 0) atomicAdd(&nz, 1);
    __syncthreads();
    if (threadIdx.x == 0) *flag = (nz == 0) ? 1 : 0;
}

// ---------------------------------------------------------------------------
// CSR build: histogram -> single-block scan -> fill
// ---------------------------------------------------------------------------
__global__ void k_hist(const int* __restrict__ ei, const int* __restrict__ flag,
                       int* __restrict__ cnt) {
    int e = blockIdx.x * blockDim.x + threadIdx.x;
    if (e < NE) {
        int d = (*flag) ? ei[2 * (NE + e)] : ei[NE + e];
        atomicAdd(&cnt[d + 1], 1);
    }
}

// in-place inclusive scan over N_NODES+1 ints, single block of 1024
__global__ void k_scan(int* __restrict__ a) {
    const int n = N_NODES + 1;
    const int T = 1024;
    const int chunk = (n + T - 1) / T;
    __shared__ int part[T];
    const int t = threadIdx.x;
    const int lo = t * chunk;
    const int hi = min(lo + chunk, n);
    int s = 0;
    for (int i = lo; i < hi; ++i) s += a[i];
    part[t] = s;
    __syncthreads();
    for (int off = 1; off < T; off <<= 1) {
        int v = (t >= off) ? part[t - off] : 0;
        __syncthreads();
        part[t] += v;
        __syncthreads();
    }
    int run = (t == 0) ? 0 : part[t - 1];
    for (int i = lo; i < hi; ++i) { run += a[i]; a[i] = run; }
}

__global__ void k_fill(const int* __restrict__ ei, const int* __restrict__ flag,
                       const int* __restrict__ ptr, int* __restrict__ cursor,
                       int* __restrict__ adj) {
    int e = blockIdx.x * blockDim.x + threadIdx.x;
    if (e < NE) {
        const int is64 = *flag;
        int d = is64 ? ei[2 * (NE + e)] : ei[NE + e];
        int s = is64 ? ei[2 * e] : ei[e];
        int pos = atomicAdd(&cursor[d], 1);
        adj[ptr[d] + pos] = s;
    }
}

// ---------------------------------------------------------------------------
// Pull aggregation: one wave (64 lanes) per node, float2 per lane (128 cols)
// writes mean = sum/max(deg,1)
// ---------------------------------------------------------------------------
__global__ void k_agg(const float* __restrict__ feat, const int* __restrict__ ptr,
                      const int* __restrict__ adj, float* __restrict__ mean) {
    const int wid = (blockIdx.x * blockDim.x + threadIdx.x) >> 6;   // node
    const int lane = threadIdx.x & 63;
    if (wid >= N_NODES) return;
    const int p0 = ptr[wid], p1 = ptr[wid + 1];
    float ax0 = 0.f, ay0 = 0.f, ax1 = 0.f, ay1 = 0.f;
    float ax2 = 0.f, ay2 = 0.f, ax3 = 0.f, ay3 = 0.f;
    int p = p0;
    for (; p + 3 < p1; p += 4) {
        int s0 = adj[p], s1 = adj[p + 1], s2 = adj[p + 2], s3 = adj[p + 3];
        float2 v0 = *(const float2*)(feat + (size_t)s0 * 128 + (lane << 1));
        float2 v1 = *(const float2*)(feat + (size_t)s1 * 128 + (lane << 1));
        float2 v2 = *(const float2*)(feat + (size_t)s2 * 128 + (lane << 1));
        float2 v3 = *(const float2*)(feat + (size_t)s3 * 128 + (lane << 1));
        ax0 += v0.x; ay0 += v0.y;
        ax1 += v1.x; ay1 += v1.y;
        ax2 += v2.x; ay2 += v2.y;
        ax3 += v3.x; ay3 += v3.y;
    }
    for (; p < p1; ++p) {
        int s0 = adj[p];
        float2 v0 = *(const float2*)(feat + (size_t)s0 * 128 + (lane << 1));
        ax0 += v0.x; ay0 += v0.y;
    }
    const float inv = 1.0f / (float)max(p1 - p0, 1);
    float2 m;
    m.x = ((ax0 + ax1) + (ax2 + ax3)) * inv;
    m.y = ((ay0 + ay1) + (ay2 + ay3)) * inv;
    *(float2*)(mean + (size_t)wid * 128 + (lane << 1)) = m;
}

// ---------------------------------------------------------------------------
// Fused linear: out[n][j] = A[n]·Wa[j] + B[n]·Wb[j] + bias[j]
//   (+ relu + exact-JAX dropout for layer 1)
// Block 256 = 16x16 threads, tile 64 nodes x 64 outs, 4x4 per thread, K=128.
// ---------------------------------------------------------------------------
template <int OD, bool RD>
__launch_bounds__(256)
__global__ void k_lin(const float* __restrict__ A, const float* __restrict__ Wa,
                      const float* __restrict__ B, const float* __restrict__ Wb,
                      const float* __restrict__ bias, float* __restrict__ out) {
    __shared__ float As[16][68];
    __shared__ float Ws[16][68];
    const int tid = threadIdx.x;
    const int tx = tid & 15;          // j group
    const int ty = tid >> 4;          // n group
    const int n0 = blockIdx.x * 64;
    const int j0 = blockIdx.y * 64;
    const int r  = tid >> 2;          // staging row 0..63
    const int c4 = tid & 3;           // staging float4 within row

    float acc[4][4] = {{0.f}};

    for (int pass = 0; pass < 2; ++pass) {
        const float* In = pass ? B : A;
        const float* W  = pass ? Wb : Wa;
        for (int kk = 0; kk < 128; kk += 16) {
            __syncthreads();
            float4 v = {0.f, 0.f, 0.f, 0.f};
            const int n = n0 + r;
            if (n < N_NODES)
                v = *(const float4*)(In + (size_t)n * 128 + kk + c4 * 4);
            As[c4 * 4 + 0][r] = v.x;
            As[c4 * 4 + 1][r] = v.y;
            As[c4 * 4 + 2][r] = v.z;
            As[c4 * 4 + 3][r] = v.w;
            float4 wv = *(const float4*)(W + (size_t)(j0 + r) * 128 + kk + c4 * 4);
            Ws[c4 * 4 + 0][r] = wv.x;
            Ws[c4 * 4 + 1][r] = wv.y;
            Ws[c4 * 4 + 2][r] = wv.z;
            Ws[c4 * 4 + 3][r] = wv.w;
            __syncthreads();
#pragma unroll
            for (int k = 0; k < 16; ++k) {
                float4 a = *(const float4*)&As[k][ty * 4];
                float4 b = *(const float4*)&Ws[k][tx * 4];
                float ar[4] = {a.x, a.y, a.z, a.w};
                float br[4] = {b.x, b.y, b.z, b.w};
#pragma unroll
                for (int i = 0; i < 4; ++i)
#pragma unroll
                    for (int jj = 0; jj < 4; ++jj)
                        acc[i][jj] += ar[i] * br[jj];
            }
        }
    }

    float bj[4];
#pragma unroll
    for (int jj = 0; jj < 4; ++jj) bj[jj] = bias[j0 + tx * 4 + jj];

#pragma unroll
    for (int i = 0; i < 4; ++i) {
        const int n = n0 + ty * 4 + i;
        if (n >= N_NODES) continue;
        float4 res;
        float* rp = &res.x;
#pragma unroll
        for (int jj = 0; jj < 4; ++jj) {
            const int j = j0 + tx * 4 + jj;
            float v = acc[i][jj] + bj[jj];
            if (RD) {
                v = fmaxf(v, 0.0f);
                const unsigned w = tf_word((unsigned)(n * 128 + j));
                v = (w & 0x80000000u) ? 0.0f : (v + v);   // /0.5 keep-scale
            }
            rp[jj] = v;
        }
        *(float4*)(out + (size_t)n * OD + j0 + tx * 4) = res;
    }
}

// ---------------------------------------------------------------------------
extern "C" void kernel_launch(void* const* d_in, const int* in_sizes, int n_in,
                              void* d_out, int out_size, void* d_ws, size_t ws_size,
                              hipStream_t stream) {
    const float* x   = (const float*)d_in[0];
    const int*   ei  = (const int*)d_in[1];
    const float* W1l = (const float*)d_in[2];
    const float* b1  = (const float*)d_in[3];
    const float* W1r = (const float*)d_in[4];
    const float* W2l = (const float*)d_in[5];
    const float* b2  = (const float*)d_in[6];
    const float* W2r = (const float*)d_in[7];
    float* out = (float*)d_out;

    char* w = (char*)d_ws;
    int* flag   = (int*)w;                       // 1 (padded to 64)
    int* ptr    = flag + 64;                     // N+1
    int* cursor = ptr + (N_NODES + 1);           // N
    int* adj    = cursor + N_NODES;              // E
    size_t foff = (((size_t)(64 + N_NODES + 1 + N_NODES + NE)) * 4 + 255) & ~(size_t)255;
    float* mean = (float*)(w + foff);            // N*128
    float* h    = mean + (size_t)N_NODES * 128;  // N*128

    hipMemsetAsync(ptr, 0, (size_t)(2 * N_NODES + 1) * sizeof(int), stream);

    k_detect<<<1, 256, 0, stream>>>(ei, flag);

    const int eb = (NE + 255) / 256;
    k_hist<<<eb, 256, 0, stream>>>(ei, flag, ptr);
    k_scan<<<1, 1024, 0, stream>>>(ptr);
    k_fill<<<eb, 256, 0, stream>>>(ei, flag, ptr, cursor, adj);

    const int ab = (N_NODES + 3) / 4;            // 4 waves per 256-block
    k_agg<<<ab, 256, 0, stream>>>(x, ptr, adj, mean);

    const int nb = (N_NODES + 63) / 64;
    k_lin<128, true><<<dim3(nb, 2), 256, 0, stream>>>(mean, W1l, x, W1r, b1, h);

    k_agg<<<ab, 256, 0, stream>>>(h, ptr, adj, mean);

    k_lin<64, false><<<dim3(nb, 1), 256, 0, stream>>>(mean, W2l, h, W2r, b2, out);
}

// Round 3
// 581.349 us; speedup vs baseline: 1.2983x; 1.2983x over previous
//
#include <hip/hip_runtime.h>
#include <hip/hip_bf16.h>

#define N_NODES 100000
#define NE      1600000
#define D_IN    128
#define D_H     128
#define D_OUT   64

#define SCAN_N   (N_NODES + 1)          // 100001
#define SCAN_TPB 256
#define SCAN_EPB (SCAN_TPB * 4)         // 1024 elems per block
#define SCAN_NB  ((SCAN_N + SCAN_EPB - 1) / SCAN_EPB)   // 98

// ---------------------------------------------------------------------------
// JAX threefry2x32, partitionable path (default since JAX 0.4.36).
// key = (0, 42). For element f: counter = (hi=0, lo=f),
// bits = out0 ^ out1. keep <=> top bit == 0  (uniform<0.5).
// ---------------------------------------------------------------------------
__device__ __forceinline__ unsigned tf_rotl(unsigned x, int d) {
    return (x << d) | (x >> (32 - d));
}

__device__ __forceinline__ unsigned tf_word(unsigned f) {
    const unsigned ks0 = 0u;
    const unsigned ks1 = 42u;
    const unsigned ks2 = 0x1BD11BDAu ^ 0u ^ 42u;
    unsigned x0 = 0u + ks0;      // counts_hi + ks[0]
    unsigned x1 = f + ks1;       // counts_lo + ks[1]
#define TF_RND(r) { x0 += x1; x1 = tf_rotl(x1, r); x1 ^= x0; }
    TF_RND(13) TF_RND(15) TF_RND(26) TF_RND(6)
    x0 += ks1; x1 += ks2 + 1u;
    TF_RND(17) TF_RND(29) TF_RND(16) TF_RND(24)
    x0 += ks2; x1 += ks0 + 2u;
    TF_RND(13) TF_RND(15) TF_RND(26) TF_RND(6)
    x0 += ks0; x1 += ks1 + 3u;
    TF_RND(17) TF_RND(29) TF_RND(16) TF_RND(24)
    x0 += ks1; x1 += ks2 + 4u;
    TF_RND(13) TF_RND(15) TF_RND(26) TF_RND(6)
    x0 += ks2; x1 += ks0 + 5u;
#undef TF_RND
    return x0 ^ x1;
}

// ---------------------------------------------------------------------------
// edge_index dtype probe: int64 data => odd 32-bit words are all 0.
// ---------------------------------------------------------------------------
__global__ void k_detect(const int* __restrict__ ei, int* __restrict__ flag) {
    __shared__ int nz;
    if (threadIdx.x == 0) nz = 0;
    __syncthreads();
    for (int i = threadIdx.x; i < 1024; i += blockDim.x)
        if (ei[2 * i + 1] != 0) atomicAdd(&nz, 1);
    __syncthreads();
    if (threadIdx.x == 0) *flag = (nz == 0) ? 1 : 0;
}

// ---------------------------------------------------------------------------
// CSR build: histogram -> 3-kernel scan -> fill
// ---------------------------------------------------------------------------
__global__ void k_hist(const int* __restrict__ ei, const int* __restrict__ flag,
                       int* __restrict__ cnt) {
    int e = blockIdx.x * blockDim.x + threadIdx.x;
    if (e < NE) {
        int d = (*flag) ? ei[2 * (NE + e)] : ei[NE + e];
        atomicAdd(&cnt[d + 1], 1);
    }
}

// pass 1: per-block sums
__global__ void k_scan_part(const int* __restrict__ a, int* __restrict__ part) {
    __shared__ int ws[SCAN_TPB / 64];
    const int t = threadIdx.x;
    const int base = blockIdx.x * SCAN_EPB + t * 4;
    int4 v = {0, 0, 0, 0};
    if (base + 3 < SCAN_N) v = *(const int4*)(a + base);
    else {
        if (base + 0 < SCAN_N) v.x = a[base + 0];
        if (base + 1 < SCAN_N) v.y = a[base + 1];
        if (base + 2 < SCAN_N) v.z = a[base + 2];
    }
    int s = v.x + v.y + v.z + v.w;
#pragma unroll
    for (int off = 32; off > 0; off >>= 1) s += __shfl_down(s, off);
    if ((t & 63) == 0) ws[t >> 6] = s;
    __syncthreads();
    if (t == 0) {
        int tot = 0;
#pragma unroll
        for (int i = 0; i < SCAN_TPB / 64; ++i) tot += ws[i];
        part[blockIdx.x] = tot;
    }
}

// pass 2: exclusive scan of SCAN_NB partials, single block of 128
__global__ void k_scan_mid(int* __restrict__ part) {
    __shared__ int sm[128];
    const int t = threadIdx.x;
    int v = (t < SCAN_NB) ? part[t] : 0;
    sm[t] = v;
    __syncthreads();
    for (int off = 1; off < 128; off <<= 1) {
        int u = (t >= off) ? sm[t - off] : 0;
        __syncthreads();
        sm[t] += u;
        __syncthreads();
    }
    if (t < SCAN_NB) part[t] = sm[t] - v;   // exclusive
}

// pass 3: in-place inclusive scan with block offsets
__global__ void k_scan_add(int* __restrict__ a, const int* __restrict__ part) {
    __shared__ int ws[SCAN_TPB / 64];
    const int t = threadIdx.x;
    const int lane = t & 63;
    const int w = t >> 6;
    const int base = blockIdx.x * SCAN_EPB + t * 4;
    int4 v = {0, 0, 0, 0};
    const bool full = (base + 3 < SCAN_N);
    if (full) v = *(const int4*)(a + base);
    else {
        if (base + 0 < SCAN_N) v.x = a[base + 0];
        if (base + 1 < SCAN_N) v.y = a[base + 1];
        if (base + 2 < SCAN_N) v.z = a[base + 2];
    }
    const int s = v.x + v.y + v.z + v.w;
    int incl = s;
#pragma unroll
    for (int off = 1; off < 64; off <<= 1) {
        int u = __shfl_up(incl, off);
        if (lane >= off) incl += u;
    }
    if (lane == 63) ws[w] = incl;
    __syncthreads();
    int woff = 0;
    for (int i = 0; i < w; ++i) woff += ws[i];
    int excl = incl - s + woff + part[blockIdx.x];
    int4 o;
    o.x = excl + v.x;
    o.y = o.x + v.y;
    o.z = o.y + v.z;
    o.w = o.z + v.w;
    if (full) *(int4*)(a + base) = o;
    else {
        if (base + 0 < SCAN_N) a[base + 0] = o.x;
        if (base + 1 < SCAN_N) a[base + 1] = o.y;
        if (base + 2 < SCAN_N) a[base + 2] = o.z;
    }
}

__global__ void k_fill(const int* __restrict__ ei, const int* __restrict__ flag,
                       const int* __restrict__ ptr, int* __restrict__ cursor,
                       int* __restrict__ adj) {
    int e = blockIdx.x * blockDim.x + threadIdx.x;
    if (e < NE) {
        const int is64 = *flag;
        int d = is64 ? ei[2 * (NE + e)] : ei[NE + e];
        int s = is64 ? ei[2 * e] : ei[e];
        int pos = atomicAdd(&cursor[d], 1);
        adj[ptr[d] + pos] = s;
    }
}

// ---------------------------------------------------------------------------
// Pull aggregation: one wave (64 lanes) per node, float2 per lane (128 cols)
// ---------------------------------------------------------------------------
__global__ void k_agg(const float* __restrict__ feat, const int* __restrict__ ptr,
                      const int* __restrict__ adj, float* __restrict__ mean) {
    const int wid = (blockIdx.x * blockDim.x + threadIdx.x) >> 6;   // node
    const int lane = threadIdx.x & 63;
    if (wid >= N_NODES) return;
    const int p0 = ptr[wid], p1 = ptr[wid + 1];
    float ax0 = 0.f, ay0 = 0.f, ax1 = 0.f, ay1 = 0.f;
    float ax2 = 0.f, ay2 = 0.f, ax3 = 0.f, ay3 = 0.f;
    int p = p0;
    for (; p + 3 < p1; p += 4) {
        int s0 = adj[p], s1 = adj[p + 1], s2 = adj[p + 2], s3 = adj[p + 3];
        float2 v0 = *(const float2*)(feat + (size_t)s0 * 128 + (lane << 1));
        float2 v1 = *(const float2*)(feat + (size_t)s1 * 128 + (lane << 1));
        float2 v2 = *(const float2*)(feat + (size_t)s2 * 128 + (lane << 1));
        float2 v3 = *(const float2*)(feat + (size_t)s3 * 128 + (lane << 1));
        ax0 += v0.x; ay0 += v0.y;
        ax1 += v1.x; ay1 += v1.y;
        ax2 += v2.x; ay2 += v2.y;
        ax3 += v3.x; ay3 += v3.y;
    }
    for (; p < p1; ++p) {
        int s0 = adj[p];
        float2 v0 = *(const float2*)(feat + (size_t)s0 * 128 + (lane << 1));
        ax0 += v0.x; ay0 += v0.y;
    }
    const float inv = 1.0f / (float)max(p1 - p0, 1);
    float2 m;
    m.x = ((ax0 + ax1) + (ax2 + ax3)) * inv;
    m.y = ((ay0 + ay1) + (ay2 + ay3)) * inv;
    *(float2*)(mean + (size_t)wid * 128 + (lane << 1)) = m;
}

// ---------------------------------------------------------------------------
// Fused linear: out[n][j] = A[n]·Wa[j] + B[n]·Wb[j] + bias[j]
//   (+ relu + exact-JAX dropout for layer 1)
// ---------------------------------------------------------------------------
template <int OD, bool RD>
__launch_bounds__(256)
__global__ void k_lin(const float* __restrict__ A, const float* __restrict__ Wa,
                      const float* __restrict__ B, const float* __restrict__ Wb,
                      const float* __restrict__ bias, float* __restrict__ out) {
    __shared__ float As[16][68];
    __shared__ float Ws[16][68];
    const int tid = threadIdx.x;
    const int tx = tid & 15;          // j group
    const int ty = tid >> 4;          // n group
    const int n0 = blockIdx.x * 64;
    const int j0 = blockIdx.y * 64;
    const int r  = tid >> 2;          // staging row 0..63
    const int c4 = tid & 3;           // staging float4 within row

    float acc[4][4] = {{0.f}};

    for (int pass = 0; pass < 2; ++pass) {
        const float* In = pass ? B : A;
        const float* W  = pass ? Wb : Wa;
        for (int kk = 0; kk < 128; kk += 16) {
            __syncthreads();
            float4 v = {0.f, 0.f, 0.f, 0.f};
            const int n = n0 + r;
            if (n < N_NODES)
                v = *(const float4*)(In + (size_t)n * 128 + kk + c4 * 4);
            As[c4 * 4 + 0][r] = v.x;
            As[c4 * 4 + 1][r] = v.y;
            As[c4 * 4 + 2][r] = v.z;
            As[c4 * 4 + 3][r] = v.w;
            float4 wv = *(const float4*)(W + (size_t)(j0 + r) * 128 + kk + c4 * 4);
            Ws[c4 * 4 + 0][r] = wv.x;
            Ws[c4 * 4 + 1][r] = wv.y;
            Ws[c4 * 4 + 2][r] = wv.z;
            Ws[c4 * 4 + 3][r] = wv.w;
            __syncthreads();
#pragma unroll
            for (int k = 0; k < 16; ++k) {
                float4 a = *(const float4*)&As[k][ty * 4];
                float4 b = *(const float4*)&Ws[k][tx * 4];
                float ar[4] = {a.x, a.y, a.z, a.w};
                float br[4] = {b.x, b.y, b.z, b.w};
#pragma unroll
                for (int i = 0; i < 4; ++i)
#pragma unroll
                    for (int jj = 0; jj < 4; ++jj)
                        acc[i][jj] += ar[i] * br[jj];
            }
        }
    }

    float bj[4];
#pragma unroll
    for (int jj = 0; jj < 4; ++jj) bj[jj] = bias[j0 + tx * 4 + jj];

#pragma unroll
    for (int i = 0; i < 4; ++i) {
        const int n = n0 + ty * 4 + i;
        if (n >= N_NODES) continue;
        float4 res;
        float* rp = &res.x;
#pragma unroll
        for (int jj = 0; jj < 4; ++jj) {
            const int j = j0 + tx * 4 + jj;
            float v = acc[i][jj] + bj[jj];
            if (RD) {
                v = fmaxf(v, 0.0f);
                const unsigned w = tf_word((unsigned)(n * 128 + j));
                v = (w & 0x80000000u) ? 0.0f : (v + v);   // /0.5 keep-scale
            }
            rp[jj] = v;
        }
        *(float4*)(out + (size_t)n * OD + j0 + tx * 4) = res;
    }
}

// ---------------------------------------------------------------------------
extern "C" void kernel_launch(void* const* d_in, const int* in_sizes, int n_in,
                              void* d_out, int out_size, void* d_ws, size_t ws_size,
                              hipStream_t stream) {
    const float* x   = (const float*)d_in[0];
    const int*   ei  = (const int*)d_in[1];
    const float* W1l = (const float*)d_in[2];
    const float* b1  = (const float*)d_in[3];
    const float* W1r = (const float*)d_in[4];
    const float* W2l = (const float*)d_in[5];
    const float* b2  = (const float*)d_in[6];
    const float* W2r = (const float*)d_in[7];
    float* out = (float*)d_out;

    char* w = (char*)d_ws;
    int* flag   = (int*)w;                       // 64 ints (flag + pad)
    int* part   = flag + 64;                     // SCAN_NB, padded to 128
    int* ptr    = part + 128;                    // N+1
    int* cursor = ptr + (N_NODES + 1);           // N
    int* adj    = cursor + N_NODES;              // E
    size_t foff = (((size_t)(64 + 128 + N_NODES + 1 + N_NODES + NE)) * 4 + 255) & ~(size_t)255;
    float* mean = (float*)(w + foff);            // N*128
    float* h    = mean + (size_t)N_NODES * 128;  // N*128

    hipMemsetAsync(ptr, 0, (size_t)(2 * N_NODES + 1) * sizeof(int), stream);

    k_detect<<<1, 256, 0, stream>>>(ei, flag);

    const int eb = (NE + 255) / 256;
    k_hist<<<eb, 256, 0, stream>>>(ei, flag, ptr);
    k_scan_part<<<SCAN_NB, SCAN_TPB, 0, stream>>>(ptr, part);
    k_scan_mid<<<1, 128, 0, stream>>>(part);
    k_scan_add<<<SCAN_NB, SCAN_TPB, 0, stream>>>(ptr, part);
    k_fill<<<eb, 256, 0, stream>>>(ei, flag, ptr, cursor, adj);

    const int ab = (N_NODES + 3) / 4;            // 4 waves per 256-block
    k_agg<<<ab, 256, 0, stream>>>(x, ptr, adj, mean);

    const int nb = (N_NODES + 63) / 64;
    k_lin<128, true><<<dim3(nb, 2), 256, 0, stream>>>(mean, W1l, x, W1r, b1, h);

    k_agg<<<ab, 256, 0, stream>>>(h, ptr, adj, mean);

    k_lin<64, false><<<dim3(nb, 1), 256, 0, stream>>>(mean, W2l, h, W2r, b2, out);
}

// Round 4
// 438.701 us; speedup vs baseline: 1.7205x; 1.3252x over previous
//
#include <hip/hip_runtime.h>
#include <hip/hip_bf16.h>

#define N_NODES 100000
#define NE      1600000

#define SCAN_N   (N_NODES + 1)
#define SCAN_TPB 256
#define SCAN_EPB (SCAN_TPB * 4)
#define SCAN_NB  ((SCAN_N + SCAN_EPB - 1) / SCAN_EPB)   // 98

typedef __attribute__((ext_vector_type(8))) short bfrag;   // 8 bf16 (4 VGPR)
typedef __attribute__((ext_vector_type(4))) float ffrag;   // 4 fp32 acc

// ---------------------------------------------------------------------------
// JAX threefry2x32, partitionable path. key=(0,42), counter=(0,f),
// bits = out0 ^ out1, keep <=> top bit == 0.
// ---------------------------------------------------------------------------
__device__ __forceinline__ unsigned tf_rotl(unsigned x, int d) {
    return (x << d) | (x >> (32 - d));
}

__device__ __forceinline__ unsigned tf_word(unsigned f) {
    const unsigned ks0 = 0u;
    const unsigned ks1 = 42u;
    const unsigned ks2 = 0x1BD11BDAu ^ 0u ^ 42u;
    unsigned x0 = 0u + ks0;
    unsigned x1 = f + ks1;
#define TF_RND(r) { x0 += x1; x1 = tf_rotl(x1, r); x1 ^= x0; }
    TF_RND(13) TF_RND(15) TF_RND(26) TF_RND(6)
    x0 += ks1; x1 += ks2 + 1u;
    TF_RND(17) TF_RND(29) TF_RND(16) TF_RND(24)
    x0 += ks2; x1 += ks0 + 2u;
    TF_RND(13) TF_RND(15) TF_RND(26) TF_RND(6)
    x0 += ks0; x1 += ks1 + 3u;
    TF_RND(17) TF_RND(29) TF_RND(16) TF_RND(24)
    x0 += ks1; x1 += ks2 + 4u;
    TF_RND(13) TF_RND(15) TF_RND(26) TF_RND(6)
    x0 += ks2; x1 += ks0 + 5u;
#undef TF_RND
    return x0 ^ x1;
}

__device__ __forceinline__ unsigned short bf_bits(float v) {
    __hip_bfloat16 b = __float2bfloat16(v);
    return *(unsigned short*)&b;
}

// ---------------------------------------------------------------------------
// edge_index dtype probe (int64 => odd 32-bit words all zero)
// ---------------------------------------------------------------------------
__global__ void k_detect(const int* __restrict__ ei, int* __restrict__ flag) {
    __shared__ int nz;
    if (threadIdx.x == 0) nz = 0;
    __syncthreads();
    for (int i = threadIdx.x; i < 1024; i += blockDim.x)
        if (ei[2 * i + 1] != 0) atomicAdd(&nz, 1);
    __syncthreads();
    if (threadIdx.x == 0) *flag = (nz == 0) ? 1 : 0;
}

// ---------------------------------------------------------------------------
// fp32 -> bf16 conversions
// ---------------------------------------------------------------------------
__global__ void k_conv(const float4* __restrict__ in, ushort4* __restrict__ out,
                       int n4) {
    int i = blockIdx.x * blockDim.x + threadIdx.x;
    if (i < n4) {
        float4 v = in[i];
        ushort4 o;
        o.x = bf_bits(v.x);
        o.y = bf_bits(v.y);
        o.z = bf_bits(v.z);
        o.w = bf_bits(v.w);
        out[i] = o;
    }
}

__global__ void k_wconv(const float* __restrict__ a, const float* __restrict__ b,
                        const float* __restrict__ c, const float* __restrict__ d,
                        __hip_bfloat16* __restrict__ o) {
    int i = blockIdx.x * blockDim.x + threadIdx.x;   // 49152 total
    if (i < 16384)      o[i] = __float2bfloat16(a[i]);
    else if (i < 32768) o[i] = __float2bfloat16(b[i - 16384]);
    else if (i < 40960) o[i] = __float2bfloat16(c[i - 32768]);
    else if (i < 49152) o[i] = __float2bfloat16(d[i - 40960]);
}

// ---------------------------------------------------------------------------
// CSR build: histogram -> 3-kernel scan -> fill
// ---------------------------------------------------------------------------
__global__ void k_hist(const int* __restrict__ ei, const int* __restrict__ flag,
                       int* __restrict__ cnt) {
    int e = blockIdx.x * blockDim.x + threadIdx.x;
    if (e < NE) {
        int d = (*flag) ? ei[2 * (NE + e)] : ei[NE + e];
        atomicAdd(&cnt[d + 1], 1);
    }
}

__global__ void k_scan_part(const int* __restrict__ a, int* __restrict__ part) {
    __shared__ int ws[SCAN_TPB / 64];
    const int t = threadIdx.x;
    const int base = blockIdx.x * SCAN_EPB + t * 4;
    int4 v = {0, 0, 0, 0};
    if (base + 3 < SCAN_N) v = *(const int4*)(a + base);
    else {
        if (base + 0 < SCAN_N) v.x = a[base + 0];
        if (base + 1 < SCAN_N) v.y = a[base + 1];
        if (base + 2 < SCAN_N) v.z = a[base + 2];
    }
    int s = v.x + v.y + v.z + v.w;
#pragma unroll
    for (int off = 32; off > 0; off >>= 1) s += __shfl_down(s, off);
    if ((t & 63) == 0) ws[t >> 6] = s;
    __syncthreads();
    if (t == 0) {
        int tot = 0;
#pragma unroll
        for (int i = 0; i < SCAN_TPB / 64; ++i) tot += ws[i];
        part[blockIdx.x] = tot;
    }
}

__global__ void k_scan_mid(int* __restrict__ part) {
    __shared__ int sm[128];
    const int t = threadIdx.x;
    int v = (t < SCAN_NB) ? part[t] : 0;
    sm[t] = v;
    __syncthreads();
    for (int off = 1; off < 128; off <<= 1) {
        int u = (t >= off) ? sm[t - off] : 0;
        __syncthreads();
        sm[t] += u;
        __syncthreads();
    }
    if (t < SCAN_NB) part[t] = sm[t] - v;   // exclusive
}

__global__ void k_scan_add(int* __restrict__ a, const int* __restrict__ part) {
    __shared__ int ws[SCAN_TPB / 64];
    const int t = threadIdx.x;
    const int lane = t & 63;
    const int w = t >> 6;
    const int base = blockIdx.x * SCAN_EPB + t * 4;
    int4 v = {0, 0, 0, 0};
    const bool full = (base + 3 < SCAN_N);
    if (full) v = *(const int4*)(a + base);
    else {
        if (base + 0 < SCAN_N) v.x = a[base + 0];
        if (base + 1 < SCAN_N) v.y = a[base + 1];
        if (base + 2 < SCAN_N) v.z = a[base + 2];
    }
    const int s = v.x + v.y + v.z + v.w;
    int incl = s;
#pragma unroll
    for (int off = 1; off < 64; off <<= 1) {
        int u = __shfl_up(incl, off);
        if (lane >= off) incl += u;
    }
    if (lane == 63) ws[w] = incl;
    __syncthreads();
    int woff = 0;
    for (int i = 0; i < w; ++i) woff += ws[i];
    int excl = incl - s + woff + part[blockIdx.x];
    int4 o;
    o.x = excl + v.x;
    o.y = o.x + v.y;
    o.z = o.y + v.z;
    o.w = o.z + v.w;
    if (full) *(int4*)(a + base) = o;
    else {
        if (base + 0 < SCAN_N) a[base + 0] = o.x;
        if (base + 1 < SCAN_N) a[base + 1] = o.y;
        if (base + 2 < SCAN_N) a[base + 2] = o.z;
    }
}

__global__ void k_fill(const int* __restrict__ ei, const int* __restrict__ flag,
                       const int* __restrict__ ptr, int* __restrict__ cursor,
                       int* __restrict__ adj) {
    int e = blockIdx.x * blockDim.x + threadIdx.x;
    if (e < NE) {
        const int is64 = *flag;
        int d = is64 ? ei[2 * (NE + e)] : ei[NE + e];
        int s = is64 ? ei[2 * e] : ei[e];
        int pos = atomicAdd(&cursor[d], 1);
        adj[ptr[d] + pos] = s;
    }
}

// ---------------------------------------------------------------------------
// bf16 pull aggregation: one wave per node, bf16x2 (4B) per lane, fp32 sums
// ---------------------------------------------------------------------------
__global__ void k_agg(const __hip_bfloat16* __restrict__ feat,
                      const int* __restrict__ ptr, const int* __restrict__ adj,
                      __hip_bfloat16* __restrict__ mean) {
    const int wid = (blockIdx.x * blockDim.x + threadIdx.x) >> 6;
    const int lane = threadIdx.x & 63;
    if (wid >= N_NODES) return;
    const int p0 = ptr[wid], p1 = ptr[wid + 1];
    float a0 = 0.f, b0 = 0.f, a1 = 0.f, b1 = 0.f;
    float a2 = 0.f, b2 = 0.f, a3 = 0.f, b3 = 0.f;
    int p = p0;
    for (; p + 3 < p1; p += 4) {
        int s0 = adj[p], s1 = adj[p + 1], s2 = adj[p + 2], s3 = adj[p + 3];
        unsigned u0 = *(const unsigned*)(feat + (size_t)s0 * 128 + lane * 2);
        unsigned u1 = *(const unsigned*)(feat + (size_t)s1 * 128 + lane * 2);
        unsigned u2 = *(const unsigned*)(feat + (size_t)s2 * 128 + lane * 2);
        unsigned u3 = *(const unsigned*)(feat + (size_t)s3 * 128 + lane * 2);
        a0 += __uint_as_float(u0 << 16); b0 += __uint_as_float(u0 & 0xffff0000u);
        a1 += __uint_as_float(u1 << 16); b1 += __uint_as_float(u1 & 0xffff0000u);
        a2 += __uint_as_float(u2 << 16); b2 += __uint_as_float(u2 & 0xffff0000u);
        a3 += __uint_as_float(u3 << 16); b3 += __uint_as_float(u3 & 0xffff0000u);
    }
    for (; p < p1; ++p) {
        int s0 = adj[p];
        unsigned u0 = *(const unsigned*)(feat + (size_t)s0 * 128 + lane * 2);
        a0 += __uint_as_float(u0 << 16); b0 += __uint_as_float(u0 & 0xffff0000u);
    }
    const float inv = 1.0f / (float)max(p1 - p0, 1);
    float m0 = ((a0 + a1) + (a2 + a3)) * inv;
    float m1 = ((b0 + b1) + (b2 + b3)) * inv;
    unsigned out = ((unsigned)bf_bits(m1) << 16) | (unsigned)bf_bits(m0);
    *(unsigned*)(mean + (size_t)wid * 128 + lane * 2) = out;
}

// ---------------------------------------------------------------------------
// Layer 1: h[n][j] = relu(mean·W1l^T + x·W1r^T + b1) * dropout, bf16 out
// MFMA 16x16x32 bf16. Block 256 = 4 waves; wave w owns j-cols [32w,32w+32).
// A/B frag: row|col = lane&15, k = (lane>>4)*8 + e. C/D: col=lane&15,
// row=(lane>>4)*4+reg  [m89].
// ---------------------------------------------------------------------------
__global__ __launch_bounds__(256) void k_lin1(
    const __hip_bfloat16* __restrict__ Am, const __hip_bfloat16* __restrict__ Ax,
    const __hip_bfloat16* __restrict__ Wl, const __hip_bfloat16* __restrict__ Wr,
    const float* __restrict__ bias, __hip_bfloat16* __restrict__ out) {
    const int tid = threadIdx.x;
    const int w  = tid >> 6;
    const int l  = tid & 63;
    const int lr = l & 15;
    const int lk = l >> 4;
    const int j0 = w * 32;
    const int n0 = blockIdx.x * 64;

    bfrag B[2][2][4];
#pragma unroll
    for (int jt = 0; jt < 2; ++jt) {
        const int jrow = j0 + jt * 16 + lr;
#pragma unroll
        for (int ks = 0; ks < 4; ++ks) {
            B[jt][0][ks] = *(const bfrag*)(Wl + jrow * 128 + ks * 32 + lk * 8);
            B[jt][1][ks] = *(const bfrag*)(Wr + jrow * 128 + ks * 32 + lk * 8);
        }
    }
    const float bj0 = bias[j0 + lr];
    const float bj1 = bias[j0 + 16 + lr];

    for (int t = 0; t < 4; ++t) {
        const int rbase = n0 + t * 16;
        int arow = rbase + lr;
        if (arow > N_NODES - 1) arow = N_NODES - 1;
        ffrag acc0 = {0.f, 0.f, 0.f, 0.f};
        ffrag acc1 = {0.f, 0.f, 0.f, 0.f};
#pragma unroll
        for (int ks = 0; ks < 4; ++ks) {
            bfrag am = *(const bfrag*)(Am + (size_t)arow * 128 + ks * 32 + lk * 8);
            bfrag ax = *(const bfrag*)(Ax + (size_t)arow * 128 + ks * 32 + lk * 8);
            acc0 = __builtin_amdgcn_mfma_f32_16x16x32_bf16(am, B[0][0][ks], acc0, 0, 0, 0);
            acc1 = __builtin_amdgcn_mfma_f32_16x16x32_bf16(am, B[1][0][ks], acc1, 0, 0, 0);
            acc0 = __builtin_amdgcn_mfma_f32_16x16x32_bf16(ax, B[0][1][ks], acc0, 0, 0, 0);
            acc1 = __builtin_amdgcn_mfma_f32_16x16x32_bf16(ax, B[1][1][ks], acc1, 0, 0, 0);
        }
#pragma unroll
        for (int r = 0; r < 4; ++r) {
            const int n = rbase + lk * 4 + r;
            if (n < N_NODES) {
                float v0 = fmaxf(acc0[r] + bj0, 0.f);
                unsigned rb0 = tf_word((unsigned)(n * 128 + j0 + lr));
                v0 = (rb0 & 0x80000000u) ? 0.f : (v0 + v0);
                out[(size_t)n * 128 + j0 + lr] = __float2bfloat16(v0);
                float v1 = fmaxf(acc1[r] + bj1, 0.f);
                unsigned rb1 = tf_word((unsigned)(n * 128 + j0 + 16 + lr));
                v1 = (rb1 & 0x80000000u) ? 0.f : (v1 + v1);
                out[(size_t)n * 128 + j0 + 16 + lr] = __float2bfloat16(v1);
            }
        }
    }
}

// ---------------------------------------------------------------------------
// Layer 2: out[n][j] = mean2·W2l^T + h·W2r^T + b2, fp32 out [N][64]
// ---------------------------------------------------------------------------
__global__ __launch_bounds__(256) void k_lin2(
    const __hip_bfloat16* __restrict__ Am, const __hip_bfloat16* __restrict__ Ah,
    const __hip_bfloat16* __restrict__ Wl, const __hip_bfloat16* __restrict__ Wr,
    const float* __restrict__ bias, float* __restrict__ out) {
    const int tid = threadIdx.x;
    const int w  = tid >> 6;
    const int l  = tid & 63;
    const int lr = l & 15;
    const int lk = l >> 4;
    const int j0 = w * 16;
    const int n0 = blockIdx.x * 64;

    bfrag Bl[4], Br[4];
    const int jrow = j0 + lr;
#pragma unroll
    for (int ks = 0; ks < 4; ++ks) {
        Bl[ks] = *(const bfrag*)(Wl + jrow * 128 + ks * 32 + lk * 8);
        Br[ks] = *(const bfrag*)(Wr + jrow * 128 + ks * 32 + lk * 8);
    }
    const float bj = bias[j0 + lr];

    for (int t = 0; t < 4; ++t) {
        const int rbase = n0 + t * 16;
        int arow = rbase + lr;
        if (arow > N_NODES - 1) arow = N_NODES - 1;
        ffrag acc = {0.f, 0.f, 0.f, 0.f};
#pragma unroll
        for (int ks = 0; ks < 4; ++ks) {
            bfrag am = *(const bfrag*)(Am + (size_t)arow * 128 + ks * 32 + lk * 8);
            bfrag ah = *(const bfrag*)(Ah + (size_t)arow * 128 + ks * 32 + lk * 8);
            acc = __builtin_amdgcn_mfma_f32_16x16x32_bf16(am, Bl[ks], acc, 0, 0, 0);
            acc = __builtin_amdgcn_mfma_f32_16x16x32_bf16(ah, Br[ks], acc, 0, 0, 0);
        }
#pragma unroll
        for (int r = 0; r < 4; ++r) {
            const int n = rbase + lk * 4 + r;
            if (n < N_NODES)
                out[(size_t)n * 64 + j0 + lr] = acc[r] + bj;
        }
    }
}

// ---------------------------------------------------------------------------
extern "C" void kernel_launch(void* const* d_in, const int* in_sizes, int n_in,
                              void* d_out, int out_size, void* d_ws, size_t ws_size,
                              hipStream_t stream) {
    const float* x   = (const float*)d_in[0];
    const int*   ei  = (const int*)d_in[1];
    const float* W1l = (const float*)d_in[2];
    const float* b1  = (const float*)d_in[3];
    const float* W1r = (const float*)d_in[4];
    const float* W2l = (const float*)d_in[5];
    const float* b2  = (const float*)d_in[6];
    const float* W2r = (const float*)d_in[7];
    float* out = (float*)d_out;

    char* w = (char*)d_ws;
    int* flag   = (int*)w;                       // 64 ints
    int* part   = flag + 64;                     // 128 ints
    int* ptr    = part + 128;                    // N+1
    int* cursor = ptr + (N_NODES + 1);           // N
    int* adj    = cursor + N_NODES;              // E
    size_t foff = (((size_t)(64 + 128 + N_NODES + 1 + N_NODES + NE)) * 4 + 255) & ~(size_t)255;
    __hip_bfloat16* wb    = (__hip_bfloat16*)(w + foff);        // 49152
    __hip_bfloat16* w1lb  = wb;
    __hip_bfloat16* w1rb  = wb + 16384;
    __hip_bfloat16* w2lb  = wb + 32768;
    __hip_bfloat16* w2rb  = wb + 40960;
    __hip_bfloat16* xb    = wb + 49152;                         // N*128
    __hip_bfloat16* meanb = xb + (size_t)N_NODES * 128;         // N*128 (reused for mean2)
    __hip_bfloat16* hb    = meanb + (size_t)N_NODES * 128;      // N*128

    hipMemsetAsync(ptr, 0, (size_t)(2 * N_NODES + 1) * sizeof(int), stream);

    const int n4 = N_NODES * 128 / 4;
    k_conv<<<(n4 + 255) / 256, 256, 0, stream>>>((const float4*)x, (ushort4*)xb, n4);
    k_wconv<<<192, 256, 0, stream>>>(W1l, W1r, W2l, W2r, wb);

    k_detect<<<1, 256, 0, stream>>>(ei, flag);

    const int eb = (NE + 255) / 256;
    k_hist<<<eb, 256, 0, stream>>>(ei, flag, ptr);
    k_scan_part<<<SCAN_NB, SCAN_TPB, 0, stream>>>(ptr, part);
    k_scan_mid<<<1, 128, 0, stream>>>(part);
    k_scan_add<<<SCAN_NB, SCAN_TPB, 0, stream>>>(ptr, part);
    k_fill<<<eb, 256, 0, stream>>>(ei, flag, ptr, cursor, adj);

    const int ab = (N_NODES + 3) / 4;
    const int nb = (N_NODES + 63) / 64;

    k_agg<<<ab, 256, 0, stream>>>(xb, ptr, adj, meanb);
    k_lin1<<<nb, 256, 0, stream>>>(meanb, xb, w1lb, w1rb, b1, hb);
    k_agg<<<ab, 256, 0, stream>>>(hb, ptr, adj, meanb);
    k_lin2<<<nb, 256, 0, stream>>>(meanb, hb, w2lb, w2rb, b2, out);
}

// Round 5
// 299.538 us; speedup vs baseline: 2.5198x; 1.4646x over previous
//
#include <hip/hip_runtime.h>
#include <hip/hip_bf16.h>

#define N_NODES 100000
#define NE      1600000

#define BINSH 7
#define NBIN  782                      // ceil(100000 / 128)
#define SEPB  16384                    // edges per binning block
#define NBLK  ((NE + SEPB - 1) / SEPB) // 98

typedef __attribute__((ext_vector_type(8))) short bfrag;   // 8 bf16 (4 VGPR)
typedef __attribute__((ext_vector_type(4))) float ffrag;   // 4 fp32 acc

// ---------------------------------------------------------------------------
// JAX threefry2x32, partitionable path. key=(0,42), counter=(0,f),
// bits = out0 ^ out1, keep <=> top bit == 0.
// ---------------------------------------------------------------------------
__device__ __forceinline__ unsigned tf_rotl(unsigned x, int d) {
    return (x << d) | (x >> (32 - d));
}

__device__ __forceinline__ unsigned tf_word(unsigned f) {
    const unsigned ks0 = 0u;
    const unsigned ks1 = 42u;
    const unsigned ks2 = 0x1BD11BDAu ^ 0u ^ 42u;
    unsigned x0 = 0u + ks0;
    unsigned x1 = f + ks1;
#define TF_RND(r) { x0 += x1; x1 = tf_rotl(x1, r); x1 ^= x0; }
    TF_RND(13) TF_RND(15) TF_RND(26) TF_RND(6)
    x0 += ks1; x1 += ks2 + 1u;
    TF_RND(17) TF_RND(29) TF_RND(16) TF_RND(24)
    x0 += ks2; x1 += ks0 + 2u;
    TF_RND(13) TF_RND(15) TF_RND(26) TF_RND(6)
    x0 += ks0; x1 += ks1 + 3u;
    TF_RND(17) TF_RND(29) TF_RND(16) TF_RND(24)
    x0 += ks1; x1 += ks2 + 4u;
    TF_RND(13) TF_RND(15) TF_RND(26) TF_RND(6)
    x0 += ks2; x1 += ks0 + 5u;
#undef TF_RND
    return x0 ^ x1;
}

__device__ __forceinline__ unsigned short bf_bits(float v) {
    __hip_bfloat16 b = __float2bfloat16(v);
    return *(unsigned short*)&b;
}

// ---------------------------------------------------------------------------
// edge_index dtype probe (int64 => odd 32-bit words all zero)
// ---------------------------------------------------------------------------
__global__ void k_detect(const int* __restrict__ ei, int* __restrict__ flag) {
    __shared__ int nz;
    if (threadIdx.x == 0) nz = 0;
    __syncthreads();
    for (int i = threadIdx.x; i < 1024; i += blockDim.x)
        if (ei[2 * i + 1] != 0) atomicAdd(&nz, 1);
    __syncthreads();
    if (threadIdx.x == 0) *flag = (nz == 0) ? 1 : 0;
}

// ---------------------------------------------------------------------------
// fp32 -> bf16 conversions
// ---------------------------------------------------------------------------
__global__ void k_conv(const float4* __restrict__ in, ushort4* __restrict__ out,
                       int n4) {
    int i = blockIdx.x * blockDim.x + threadIdx.x;
    if (i < n4) {
        float4 v = in[i];
        ushort4 o;
        o.x = bf_bits(v.x);
        o.y = bf_bits(v.y);
        o.z = bf_bits(v.z);
        o.w = bf_bits(v.w);
        out[i] = o;
    }
}

__global__ void k_wconv(const float* __restrict__ a, const float* __restrict__ b,
                        const float* __restrict__ c, const float* __restrict__ d,
                        __hip_bfloat16* __restrict__ o) {
    int i = blockIdx.x * blockDim.x + threadIdx.x;   // 49152 total
    if (i < 16384)      o[i] = __float2bfloat16(a[i]);
    else if (i < 32768) o[i] = __float2bfloat16(b[i - 16384]);
    else if (i < 40960) o[i] = __float2bfloat16(c[i - 32768]);
    else if (i < 49152) o[i] = __float2bfloat16(d[i - 40960]);
}

// ---------------------------------------------------------------------------
// Binned CSR build. bin = dst >> 7 (128 nodes/bin).
// 1) k_bincnt:     LDS hist per block -> 1 global atomic per (block,bin)
// 2) k_binscan:    exclusive scan of bin counts -> binptr, bincur
// 3) k_binscatter: LDS hist -> per-(block,bin) reservation -> dense pair runs
// 4) k_bin2csr:    per-bin local count/scan/scatter -> ptr + adj (CSR)
// ---------------------------------------------------------------------------
__global__ __launch_bounds__(1024) void k_bincnt(const int* __restrict__ ei,
        const int* __restrict__ flag, int* __restrict__ bincnt) {
    __shared__ int h[NBIN];
    for (int i = threadIdx.x; i < NBIN; i += 1024) h[i] = 0;
    __syncthreads();
    const int is64 = *flag;
    const int e0 = blockIdx.x * SEPB + threadIdx.x;
#pragma unroll
    for (int k = 0; k < 16; ++k) {
        int e = e0 + k * 1024;
        if (e < NE) {
            int d = is64 ? ei[2 * (NE + e)] : ei[NE + e];
            atomicAdd(&h[d >> BINSH], 1);
        }
    }
    __syncthreads();
    for (int i = threadIdx.x; i < NBIN; i += 1024)
        if (h[i]) atomicAdd(&bincnt[i], h[i]);
}

__global__ __launch_bounds__(1024) void k_binscan(const int* __restrict__ bincnt,
        int* __restrict__ binptr, int* __restrict__ bincur) {
    __shared__ int sm[1024];
    const int t = threadIdx.x;
    int v = (t < NBIN) ? bincnt[t] : 0;
    sm[t] = v;
    __syncthreads();
    for (int off = 1; off < 1024; off <<= 1) {
        int u = (t >= off) ? sm[t - off] : 0;
        __syncthreads();
        sm[t] += u;
        __syncthreads();
    }
    if (t <= NBIN) {
        int ex = (t == 0) ? 0 : sm[t - 1];
        binptr[t] = ex;
        if (t < NBIN) bincur[t] = ex;
    }
}

__global__ __launch_bounds__(1024) void k_binscatter(const int* __restrict__ ei,
        const int* __restrict__ flag, int* __restrict__ bincur,
        int2* __restrict__ pairs) {
    __shared__ int h[NBIN];
    __shared__ int lbase[NBIN];
    for (int i = threadIdx.x; i < NBIN; i += 1024) h[i] = 0;
    __syncthreads();
    const int is64 = *flag;
    const int e0 = blockIdx.x * SEPB + threadIdx.x;
    int d[16], s[16];
#pragma unroll
    for (int k = 0; k < 16; ++k) {
        int e = e0 + k * 1024;
        if (e < NE) {
            d[k] = is64 ? ei[2 * (NE + e)] : ei[NE + e];
            s[k] = is64 ? ei[2 * e]        : ei[e];
            atomicAdd(&h[d[k] >> BINSH], 1);
        } else {
            d[k] = -1; s[k] = 0;
        }
    }
    __syncthreads();
    for (int i = threadIdx.x; i < NBIN; i += 1024) {
        int c = h[i];
        lbase[i] = c ? atomicAdd(&bincur[i], c) : 0;
        h[i] = 0;                      // reuse as intra-block rank counter
    }
    __syncthreads();
#pragma unroll
    for (int k = 0; k < 16; ++k) {
        if (d[k] >= 0) {
            int b = d[k] >> BINSH;
            int r = atomicAdd(&h[b], 1);
            pairs[lbase[b] + r] = make_int2(s[k], d[k]);
        }
    }
}

__global__ __launch_bounds__(256) void k_bin2csr(const int2* __restrict__ pairs,
        const int* __restrict__ binptr, int* __restrict__ ptr,
        int* __restrict__ adj) {
    __shared__ int cnt[128];
    __shared__ int sc[128];
    __shared__ int woff[128];
    const int b = blockIdx.x;
    const int base = binptr[b];
    const int nb = binptr[b + 1] - base;
    const int t = threadIdx.x;
    if (t < 128) cnt[t] = 0;
    __syncthreads();
    for (int i = t; i < nb; i += 256)
        atomicAdd(&cnt[pairs[base + i].y & 127], 1);
    __syncthreads();
    if (t < 128) sc[t] = cnt[t];
    __syncthreads();
    for (int o = 1; o < 128; o <<= 1) {
        int u = 0;
        if (t < 128 && t >= o) u = sc[t - o];
        __syncthreads();
        if (t < 128) sc[t] += u;
        __syncthreads();
    }
    if (t < 128) {
        int ex = sc[t] - cnt[t];       // exclusive local offset
        int node = b * 128 + t;
        if (node <= N_NODES) ptr[node] = base + ex;
        woff[t] = ex;
    }
    __syncthreads();
    for (int i = t; i < nb; i += 256) {
        int2 p = pairs[base + i];
        int r = atomicAdd(&woff[p.y & 127], 1);
        adj[base + r] = p.x;           // scatter within this bin's ~8KB window
    }
}

// ---------------------------------------------------------------------------
// bf16 pull aggregation: one wave per node, bf16x2 (4B) per lane, fp32 sums
// ---------------------------------------------------------------------------
__global__ void k_agg(const __hip_bfloat16* __restrict__ feat,
                      const int* __restrict__ ptr, const int* __restrict__ adj,
                      __hip_bfloat16* __restrict__ mean) {
    const int wid = (blockIdx.x * blockDim.x + threadIdx.x) >> 6;
    const int lane = threadIdx.x & 63;
    if (wid >= N_NODES) return;
    const int p0 = ptr[wid], p1 = ptr[wid + 1];
    float a0 = 0.f, b0 = 0.f, a1 = 0.f, b1 = 0.f;
    float a2 = 0.f, b2 = 0.f, a3 = 0.f, b3 = 0.f;
    int p = p0;
    for (; p + 3 < p1; p += 4) {
        int s0 = adj[p], s1 = adj[p + 1], s2 = adj[p + 2], s3 = adj[p + 3];
        unsigned u0 = *(const unsigned*)(feat + (size_t)s0 * 128 + lane * 2);
        unsigned u1 = *(const unsigned*)(feat + (size_t)s1 * 128 + lane * 2);
        unsigned u2 = *(const unsigned*)(feat + (size_t)s2 * 128 + lane * 2);
        unsigned u3 = *(const unsigned*)(feat + (size_t)s3 * 128 + lane * 2);
        a0 += __uint_as_float(u0 << 16); b0 += __uint_as_float(u0 & 0xffff0000u);
        a1 += __uint_as_float(u1 << 16); b1 += __uint_as_float(u1 & 0xffff0000u);
        a2 += __uint_as_float(u2 << 16); b2 += __uint_as_float(u2 & 0xffff0000u);
        a3 += __uint_as_float(u3 << 16); b3 += __uint_as_float(u3 & 0xffff0000u);
    }
    for (; p < p1; ++p) {
        int s0 = adj[p];
        unsigned u0 = *(const unsigned*)(feat + (size_t)s0 * 128 + lane * 2);
        a0 += __uint_as_float(u0 << 16); b0 += __uint_as_float(u0 & 0xffff0000u);
    }
    const float inv = 1.0f / (float)max(p1 - p0, 1);
    float m0 = ((a0 + a1) + (a2 + a3)) * inv;
    float m1 = ((b0 + b1) + (b2 + b3)) * inv;
    unsigned out = ((unsigned)bf_bits(m1) << 16) | (unsigned)bf_bits(m0);
    *(unsigned*)(mean + (size_t)wid * 128 + lane * 2) = out;
}

// ---------------------------------------------------------------------------
// Layer 1: h[n][j] = relu(mean·W1l^T + x·W1r^T + b1) * dropout, bf16 out
// MFMA 16x16x32 bf16; C/D: col=lane&15, row=(lane>>4)*4+reg  [m89].
// ---------------------------------------------------------------------------
__global__ __launch_bounds__(256) void k_lin1(
    const __hip_bfloat16* __restrict__ Am, const __hip_bfloat16* __restrict__ Ax,
    const __hip_bfloat16* __restrict__ Wl, const __hip_bfloat16* __restrict__ Wr,
    const float* __restrict__ bias, __hip_bfloat16* __restrict__ out) {
    const int tid = threadIdx.x;
    const int w  = tid >> 6;
    const int l  = tid & 63;
    const int lr = l & 15;
    const int lk = l >> 4;
    const int j0 = w * 32;
    const int n0 = blockIdx.x * 64;

    bfrag B[2][2][4];
#pragma unroll
    for (int jt = 0; jt < 2; ++jt) {
        const int jrow = j0 + jt * 16 + lr;
#pragma unroll
        for (int ks = 0; ks < 4; ++ks) {
            B[jt][0][ks] = *(const bfrag*)(Wl + jrow * 128 + ks * 32 + lk * 8);
            B[jt][1][ks] = *(const bfrag*)(Wr + jrow * 128 + ks * 32 + lk * 8);
        }
    }
    const float bj0 = bias[j0 + lr];
    const float bj1 = bias[j0 + 16 + lr];

    for (int t = 0; t < 4; ++t) {
        const int rbase = n0 + t * 16;
        int arow = rbase + lr;
        if (arow > N_NODES - 1) arow = N_NODES - 1;
        ffrag acc0 = {0.f, 0.f, 0.f, 0.f};
        ffrag acc1 = {0.f, 0.f, 0.f, 0.f};
#pragma unroll
        for (int ks = 0; ks < 4; ++ks) {
            bfrag am = *(const bfrag*)(Am + (size_t)arow * 128 + ks * 32 + lk * 8);
            bfrag ax = *(const bfrag*)(Ax + (size_t)arow * 128 + ks * 32 + lk * 8);
            acc0 = __builtin_amdgcn_mfma_f32_16x16x32_bf16(am, B[0][0][ks], acc0, 0, 0, 0);
            acc1 = __builtin_amdgcn_mfma_f32_16x16x32_bf16(am, B[1][0][ks], acc1, 0, 0, 0);
            acc0 = __builtin_amdgcn_mfma_f32_16x16x32_bf16(ax, B[0][1][ks], acc0, 0, 0, 0);
            acc1 = __builtin_amdgcn_mfma_f32_16x16x32_bf16(ax, B[1][1][ks], acc1, 0, 0, 0);
        }
#pragma unroll
        for (int r = 0; r < 4; ++r) {
            const int n = rbase + lk * 4 + r;
            if (n < N_NODES) {
                float v0 = fmaxf(acc0[r] + bj0, 0.f);
                unsigned rb0 = tf_word((unsigned)(n * 128 + j0 + lr));
                v0 = (rb0 & 0x80000000u) ? 0.f : (v0 + v0);
                out[(size_t)n * 128 + j0 + lr] = __float2bfloat16(v0);
                float v1 = fmaxf(acc1[r] + bj1, 0.f);
                unsigned rb1 = tf_word((unsigned)(n * 128 + j0 + 16 + lr));
                v1 = (rb1 & 0x80000000u) ? 0.f : (v1 + v1);
                out[(size_t)n * 128 + j0 + 16 + lr] = __float2bfloat16(v1);
            }
        }
    }
}

// ---------------------------------------------------------------------------
// Layer 2: out[n][j] = mean2·W2l^T + h·W2r^T + b2, fp32 out [N][64]
// ---------------------------------------------------------------------------
__global__ __launch_bounds__(256) void k_lin2(
    const __hip_bfloat16* __restrict__ Am, const __hip_bfloat16* __restrict__ Ah,
    const __hip_bfloat16* __restrict__ Wl, const __hip_bfloat16* __restrict__ Wr,
    const float* __restrict__ bias, float* __restrict__ out) {
    const int tid = threadIdx.x;
    const int w  = tid >> 6;
    const int l  = tid & 63;
    const int lr = l & 15;
    const int lk = l >> 4;
    const int j0 = w * 16;
    const int n0 = blockIdx.x * 64;

    bfrag Bl[4], Br[4];
    const int jrow = j0 + lr;
#pragma unroll
    for (int ks = 0; ks < 4; ++ks) {
        Bl[ks] = *(const bfrag*)(Wl + jrow * 128 + ks * 32 + lk * 8);
        Br[ks] = *(const bfrag*)(Wr + jrow * 128 + ks * 32 + lk * 8);
    }
    const float bj = bias[j0 + lr];

    for (int t = 0; t < 4; ++t) {
        const int rbase = n0 + t * 16;
        int arow = rbase + lr;
        if (arow > N_NODES - 1) arow = N_NODES - 1;
        ffrag acc = {0.f, 0.f, 0.f, 0.f};
#pragma unroll
        for (int ks = 0; ks < 4; ++ks) {
            bfrag am = *(const bfrag*)(Am + (size_t)arow * 128 + ks * 32 + lk * 8);
            bfrag ah = *(const bfrag*)(Ah + (size_t)arow * 128 + ks * 32 + lk * 8);
            acc = __builtin_amdgcn_mfma_f32_16x16x32_bf16(am, Bl[ks], acc, 0, 0, 0);
            acc = __builtin_amdgcn_mfma_f32_16x16x32_bf16(ah, Br[ks], acc, 0, 0, 0);
        }
#pragma unroll
        for (int r = 0; r < 4; ++r) {
            const int n = rbase + lk * 4 + r;
            if (n < N_NODES)
                out[(size_t)n * 64 + j0 + lr] = acc[r] + bj;
        }
    }
}

// ---------------------------------------------------------------------------
extern "C" void kernel_launch(void* const* d_in, const int* in_sizes, int n_in,
                              void* d_out, int out_size, void* d_ws, size_t ws_size,
                              hipStream_t stream) {
    const float* x   = (const float*)d_in[0];
    const int*   ei  = (const int*)d_in[1];
    const float* W1l = (const float*)d_in[2];
    const float* b1  = (const float*)d_in[3];
    const float* W1r = (const float*)d_in[4];
    const float* W2l = (const float*)d_in[5];
    const float* b2  = (const float*)d_in[6];
    const float* W2r = (const float*)d_in[7];
    float* out = (float*)d_out;

    char* w = (char*)d_ws;
    int* flag   = (int*)w;                       // 64 ints
    int* bincnt = flag + 64;                     // 1024
    int* binptr = bincnt + 1024;                 // 1088 (NBIN+1 used)
    int* bincur = binptr + 1088;                 // 1024
    int* ptr    = bincur + 1024;                 // N+1
    int* adj    = ptr + (N_NODES + 1);           // NE
    size_t foff = (((size_t)(64 + 1024 + 1088 + 1024 + N_NODES + 1 + NE)) * 4 + 255)
                  & ~(size_t)255;
    __hip_bfloat16* wb    = (__hip_bfloat16*)(w + foff);        // 49152
    __hip_bfloat16* w1lb  = wb;
    __hip_bfloat16* w1rb  = wb + 16384;
    __hip_bfloat16* w2lb  = wb + 32768;
    __hip_bfloat16* w2rb  = wb + 40960;
    __hip_bfloat16* xb    = wb + 49152;                         // N*128
    __hip_bfloat16* meanb = xb + (size_t)N_NODES * 128;         // N*128
    __hip_bfloat16* hb    = meanb + (size_t)N_NODES * 128;      // N*128
    int2* pairs = (int2*)hb;   // overlay: pairs (12.8MB) dead before hb is written

    hipMemsetAsync(bincnt, 0, 1024 * sizeof(int), stream);

    const int n4 = N_NODES * 128 / 4;
    k_conv<<<(n4 + 255) / 256, 256, 0, stream>>>((const float4*)x, (ushort4*)xb, n4);
    k_wconv<<<192, 256, 0, stream>>>(W1l, W1r, W2l, W2r, wb);

    k_detect<<<1, 256, 0, stream>>>(ei, flag);

    k_bincnt<<<NBLK, 1024, 0, stream>>>(ei, flag, bincnt);
    k_binscan<<<1, 1024, 0, stream>>>(bincnt, binptr, bincur);
    k_binscatter<<<NBLK, 1024, 0, stream>>>(ei, flag, bincur, pairs);
    k_bin2csr<<<NBIN, 256, 0, stream>>>(pairs, binptr, ptr, adj);

    const int ab = (N_NODES + 3) / 4;
    const int nb = (N_NODES + 63) / 64;

    k_agg<<<ab, 256, 0, stream>>>(xb, ptr, adj, meanb);
    k_lin1<<<nb, 256, 0, stream>>>(meanb, xb, w1lb, w1rb, b1, hb);
    k_agg<<<ab, 256, 0, stream>>>(hb, ptr, adj, meanb);
    k_lin2<<<nb, 256, 0, stream>>>(meanb, hb, w2lb, w2rb, b2, out);
}

// Round 6
// 254.027 us; speedup vs baseline: 2.9713x; 1.1792x over previous
//
#include <hip/hip_runtime.h>
#include <hip/hip_bf16.h>

#define N_NODES 100000
#define NE      1600000

#define BINSH 7
#define NBIN  782                      // ceil(100000 / 128)
#define BCAP  3072                     // max edges/bin (avg 2046, sigma~45)
#define SEPB  16384                    // edges per binning block
#define NBLK  ((NE + SEPB - 1) / SEPB) // 98

typedef __attribute__((ext_vector_type(8))) short bfrag;   // 8 bf16 (4 VGPR)
typedef __attribute__((ext_vector_type(4))) float ffrag;   // 4 fp32 acc

#define BFLO(u) __uint_as_float((u) << 16)
#define BFHI(u) __uint_as_float((u) & 0xffff0000u)

// ---------------------------------------------------------------------------
// JAX threefry2x32, partitionable path. key=(0,42), counter=(0,f),
// bits = out0 ^ out1, keep <=> top bit == 0.
// ---------------------------------------------------------------------------
__device__ __forceinline__ unsigned tf_rotl(unsigned x, int d) {
    return (x << d) | (x >> (32 - d));
}

__device__ __forceinline__ unsigned tf_word(unsigned f) {
    const unsigned ks0 = 0u;
    const unsigned ks1 = 42u;
    const unsigned ks2 = 0x1BD11BDAu ^ 0u ^ 42u;
    unsigned x0 = 0u + ks0;
    unsigned x1 = f + ks1;
#define TF_RND(r) { x0 += x1; x1 = tf_rotl(x1, r); x1 ^= x0; }
    TF_RND(13) TF_RND(15) TF_RND(26) TF_RND(6)
    x0 += ks1; x1 += ks2 + 1u;
    TF_RND(17) TF_RND(29) TF_RND(16) TF_RND(24)
    x0 += ks2; x1 += ks0 + 2u;
    TF_RND(13) TF_RND(15) TF_RND(26) TF_RND(6)
    x0 += ks0; x1 += ks1 + 3u;
    TF_RND(17) TF_RND(29) TF_RND(16) TF_RND(24)
    x0 += ks1; x1 += ks2 + 4u;
    TF_RND(13) TF_RND(15) TF_RND(26) TF_RND(6)
    x0 += ks2; x1 += ks0 + 5u;
#undef TF_RND
    return x0 ^ x1;
}

__device__ __forceinline__ unsigned short bf_bits(float v) {
    __hip_bfloat16 b = __float2bfloat16(v);
    return *(unsigned short*)&b;
}

// ---------------------------------------------------------------------------
// edge_index dtype probe (int64 => odd 32-bit words all zero)
// ---------------------------------------------------------------------------
__global__ void k_detect(const int* __restrict__ ei, int* __restrict__ flag) {
    __shared__ int nz;
    if (threadIdx.x == 0) nz = 0;
    __syncthreads();
    for (int i = threadIdx.x; i < 1024; i += blockDim.x)
        if (ei[2 * i + 1] != 0) atomicAdd(&nz, 1);
    __syncthreads();
    if (threadIdx.x == 0) *flag = (nz == 0) ? 1 : 0;
}

// ---------------------------------------------------------------------------
// fp32 -> bf16 conversions
// ---------------------------------------------------------------------------
__global__ void k_conv(const float4* __restrict__ in, ushort4* __restrict__ out,
                       int n4) {
    int i = blockIdx.x * blockDim.x + threadIdx.x;
    if (i < n4) {
        float4 v = in[i];
        ushort4 o;
        o.x = bf_bits(v.x);
        o.y = bf_bits(v.y);
        o.z = bf_bits(v.z);
        o.w = bf_bits(v.w);
        out[i] = o;
    }
}

__global__ void k_wconv(const float* __restrict__ a, const float* __restrict__ b,
                        const float* __restrict__ c, const float* __restrict__ d,
                        __hip_bfloat16* __restrict__ o) {
    int i = blockIdx.x * blockDim.x + threadIdx.x;   // 49152 total
    if (i < 16384)      o[i] = __float2bfloat16(a[i]);
    else if (i < 32768) o[i] = __float2bfloat16(b[i - 16384]);
    else if (i < 40960) o[i] = __float2bfloat16(c[i - 32768]);
    else if (i < 49152) o[i] = __float2bfloat16(d[i - 40960]);
}

// ---------------------------------------------------------------------------
// Binned CSR build (single edge pass + per-bin compaction):
// 1) k_binscatter: LDS hist -> per-(block,bin) reservation in fixed-cap bins
// 2) k_binscan:    exclusive scan of bin counts -> binptr
// 3) k_bin2csr:    per-bin local count/scan/scatter -> ptr + adj (CSR)
// ---------------------------------------------------------------------------
__global__ __launch_bounds__(1024) void k_binscatter(const int* __restrict__ ei,
        const int* __restrict__ flag, int* __restrict__ bincur,
        int2* __restrict__ pairs) {
    __shared__ int h[NBIN];
    __shared__ int lbase[NBIN];
    for (int i = threadIdx.x; i < NBIN; i += 1024) h[i] = 0;
    __syncthreads();
    const int is64 = *flag;
    const int e0 = blockIdx.x * SEPB + threadIdx.x;
    int d[16], s[16];
#pragma unroll
    for (int k = 0; k < 16; ++k) {
        int e = e0 + k * 1024;
        if (e < NE) {
            d[k] = is64 ? ei[2 * (NE + e)] : ei[NE + e];
            s[k] = is64 ? ei[2 * e]        : ei[e];
            atomicAdd(&h[d[k] >> BINSH], 1);
        } else {
            d[k] = -1; s[k] = 0;
        }
    }
    __syncthreads();
    for (int i = threadIdx.x; i < NBIN; i += 1024) {
        int c = h[i];
        lbase[i] = c ? atomicAdd(&bincur[i], c) : 0;
        h[i] = 0;                      // reuse as intra-block rank counter
    }
    __syncthreads();
#pragma unroll
    for (int k = 0; k < 16; ++k) {
        if (d[k] >= 0) {
            int b = d[k] >> BINSH;
            int r = atomicAdd(&h[b], 1);
            pairs[(size_t)b * BCAP + lbase[b] + r] = make_int2(s[k], d[k]);
        }
    }
}

__global__ __launch_bounds__(1024) void k_binscan(const int* __restrict__ bincnt,
        int* __restrict__ binptr) {
    __shared__ int sm[1024];
    const int t = threadIdx.x;
    int v = (t < NBIN) ? bincnt[t] : 0;
    sm[t] = v;
    __syncthreads();
    for (int off = 1; off < 1024; off <<= 1) {
        int u = (t >= off) ? sm[t - off] : 0;
        __syncthreads();
        sm[t] += u;
        __syncthreads();
    }
    if (t < NBIN) binptr[t] = sm[t] - v;   // exclusive
}

__global__ __launch_bounds__(256) void k_bin2csr(const int2* __restrict__ pairs,
        const int* __restrict__ binptr, const int* __restrict__ bincnt,
        int* __restrict__ ptr, int* __restrict__ adj) {
    __shared__ int cnt[128];
    __shared__ int sc[128];
    __shared__ int woff[128];
    const int b = blockIdx.x;
    const int base = binptr[b];
    const int nb = bincnt[b];
    const int2* pb = pairs + (size_t)b * BCAP;
    const int t = threadIdx.x;
    if (t < 128) cnt[t] = 0;
    __syncthreads();
    for (int i = t; i < nb; i += 256)
        atomicAdd(&cnt[pb[i].y & 127], 1);
    __syncthreads();
    if (t < 128) sc[t] = cnt[t];
    __syncthreads();
    for (int o = 1; o < 128; o <<= 1) {
        int u = 0;
        if (t < 128 && t >= o) u = sc[t - o];
        __syncthreads();
        if (t < 128) sc[t] += u;
        __syncthreads();
    }
    if (t < 128) {
        int ex = sc[t] - cnt[t];       // exclusive local offset
        int node = b * 128 + t;
        if (node <= N_NODES) ptr[node] = base + ex;
        woff[t] = ex;
    }
    __syncthreads();
    for (int i = t; i < nb; i += 256) {
        int2 p = pb[i];
        int r = atomicAdd(&woff[p.y & 127], 1);
        adj[base + r] = p.x;           // scatter within this bin's window
    }
}

// ---------------------------------------------------------------------------
// bf16 pull aggregation, 128-dim: one wave per node, bf16x2 per lane,
// unroll 8 for memory-level parallelism
// ---------------------------------------------------------------------------
__global__ void k_agg(const __hip_bfloat16* __restrict__ feat,
                      const int* __restrict__ ptr, const int* __restrict__ adj,
                      __hip_bfloat16* __restrict__ mean) {
    const int wid = (blockIdx.x * blockDim.x + threadIdx.x) >> 6;
    const int lane = threadIdx.x & 63;
    if (wid >= N_NODES) return;
    const int p0 = ptr[wid], p1 = ptr[wid + 1];
    float a0 = 0.f, b0 = 0.f, a1 = 0.f, b1 = 0.f;
    float a2 = 0.f, b2 = 0.f, a3 = 0.f, b3 = 0.f;
    int p = p0;
    for (; p + 7 < p1; p += 8) {
        int s0 = adj[p],     s1 = adj[p + 1], s2 = adj[p + 2], s3 = adj[p + 3];
        int s4 = adj[p + 4], s5 = adj[p + 5], s6 = adj[p + 6], s7 = adj[p + 7];
        unsigned u0 = *(const unsigned*)(feat + (size_t)s0 * 128 + lane * 2);
        unsigned u1 = *(const unsigned*)(feat + (size_t)s1 * 128 + lane * 2);
        unsigned u2 = *(const unsigned*)(feat + (size_t)s2 * 128 + lane * 2);
        unsigned u3 = *(const unsigned*)(feat + (size_t)s3 * 128 + lane * 2);
        unsigned u4 = *(const unsigned*)(feat + (size_t)s4 * 128 + lane * 2);
        unsigned u5 = *(const unsigned*)(feat + (size_t)s5 * 128 + lane * 2);
        unsigned u6 = *(const unsigned*)(feat + (size_t)s6 * 128 + lane * 2);
        unsigned u7 = *(const unsigned*)(feat + (size_t)s7 * 128 + lane * 2);
        a0 += BFLO(u0); b0 += BFHI(u0); a1 += BFLO(u1); b1 += BFHI(u1);
        a2 += BFLO(u2); b2 += BFHI(u2); a3 += BFLO(u3); b3 += BFHI(u3);
        a0 += BFLO(u4); b0 += BFHI(u4); a1 += BFLO(u5); b1 += BFHI(u5);
        a2 += BFLO(u6); b2 += BFHI(u6); a3 += BFLO(u7); b3 += BFHI(u7);
    }
    for (; p + 3 < p1; p += 4) {
        int s0 = adj[p], s1 = adj[p + 1], s2 = adj[p + 2], s3 = adj[p + 3];
        unsigned u0 = *(const unsigned*)(feat + (size_t)s0 * 128 + lane * 2);
        unsigned u1 = *(const unsigned*)(feat + (size_t)s1 * 128 + lane * 2);
        unsigned u2 = *(const unsigned*)(feat + (size_t)s2 * 128 + lane * 2);
        unsigned u3 = *(const unsigned*)(feat + (size_t)s3 * 128 + lane * 2);
        a0 += BFLO(u0); b0 += BFHI(u0); a1 += BFLO(u1); b1 += BFHI(u1);
        a2 += BFLO(u2); b2 += BFHI(u2); a3 += BFLO(u3); b3 += BFHI(u3);
    }
    for (; p < p1; ++p) {
        int s0 = adj[p];
        unsigned u0 = *(const unsigned*)(feat + (size_t)s0 * 128 + lane * 2);
        a0 += BFLO(u0); b0 += BFHI(u0);
    }
    const float inv = 1.0f / (float)max(p1 - p0, 1);
    float m0 = ((a0 + a1) + (a2 + a3)) * inv;
    float m1 = ((b0 + b1) + (b2 + b3)) * inv;
    unsigned o = ((unsigned)bf_bits(m1) << 16) | (unsigned)bf_bits(m0);
    *(unsigned*)(mean + (size_t)wid * 128 + lane * 2) = o;
}

// ---------------------------------------------------------------------------
// bf16 pull aggregation, 64-dim (y2 table): 32 lanes per node, 2 nodes/wave
// ---------------------------------------------------------------------------
__global__ void k_agg2(const __hip_bfloat16* __restrict__ feat,
                       const int* __restrict__ ptr, const int* __restrict__ adj,
                       __hip_bfloat16* __restrict__ mean) {
    const int node = (blockIdx.x * blockDim.x + threadIdx.x) >> 5;
    const int sl = threadIdx.x & 31;
    if (node >= N_NODES) return;
    const int p0 = ptr[node], p1 = ptr[node + 1];
    float a0 = 0.f, b0 = 0.f, a1 = 0.f, b1 = 0.f;
    float a2 = 0.f, b2 = 0.f, a3 = 0.f, b3 = 0.f;
    int p = p0;
    for (; p + 7 < p1; p += 8) {
        int s0 = adj[p],     s1 = adj[p + 1], s2 = adj[p + 2], s3 = adj[p + 3];
        int s4 = adj[p + 4], s5 = adj[p + 5], s6 = adj[p + 6], s7 = adj[p + 7];
        unsigned u0 = *(const unsigned*)(feat + (size_t)s0 * 64 + sl * 2);
        unsigned u1 = *(const unsigned*)(feat + (size_t)s1 * 64 + sl * 2);
        unsigned u2 = *(const unsigned*)(feat + (size_t)s2 * 64 + sl * 2);
        unsigned u3 = *(const unsigned*)(feat + (size_t)s3 * 64 + sl * 2);
        unsigned u4 = *(const unsigned*)(feat + (size_t)s4 * 64 + sl * 2);
        unsigned u5 = *(const unsigned*)(feat + (size_t)s5 * 64 + sl * 2);
        unsigned u6 = *(const unsigned*)(feat + (size_t)s6 * 64 + sl * 2);
        unsigned u7 = *(const unsigned*)(feat + (size_t)s7 * 64 + sl * 2);
        a0 += BFLO(u0); b0 += BFHI(u0); a1 += BFLO(u1); b1 += BFHI(u1);
        a2 += BFLO(u2); b2 += BFHI(u2); a3 += BFLO(u3); b3 += BFHI(u3);
        a0 += BFLO(u4); b0 += BFHI(u4); a1 += BFLO(u5); b1 += BFHI(u5);
        a2 += BFLO(u6); b2 += BFHI(u6); a3 += BFLO(u7); b3 += BFHI(u7);
    }
    for (; p + 3 < p1; p += 4) {
        int s0 = adj[p], s1 = adj[p + 1], s2 = adj[p + 2], s3 = adj[p + 3];
        unsigned u0 = *(const unsigned*)(feat + (size_t)s0 * 64 + sl * 2);
        unsigned u1 = *(const unsigned*)(feat + (size_t)s1 * 64 + sl * 2);
        unsigned u2 = *(const unsigned*)(feat + (size_t)s2 * 64 + sl * 2);
        unsigned u3 = *(const unsigned*)(feat + (size_t)s3 * 64 + sl * 2);
        a0 += BFLO(u0); b0 += BFHI(u0); a1 += BFLO(u1); b1 += BFHI(u1);
        a2 += BFLO(u2); b2 += BFHI(u2); a3 += BFLO(u3); b3 += BFHI(u3);
    }
    for (; p < p1; ++p) {
        int s0 = adj[p];
        unsigned u0 = *(const unsigned*)(feat + (size_t)s0 * 64 + sl * 2);
        a0 += BFLO(u0); b0 += BFHI(u0);
    }
    const float inv = 1.0f / (float)max(p1 - p0, 1);
    float m0 = ((a0 + a1) + (a2 + a3)) * inv;
    float m1 = ((b0 + b1) + (b2 + b3)) * inv;
    unsigned o = ((unsigned)bf_bits(m1) << 16) | (unsigned)bf_bits(m0);
    *(unsigned*)(mean + (size_t)node * 64 + sl * 2) = o;
}

// ---------------------------------------------------------------------------
// Layer 1: h[n][j] = relu(mean·W1l^T + x·W1r^T + b1) * dropout, bf16 out
// MFMA 16x16x32 bf16; C/D: col=lane&15, row=(lane>>4)*4+reg  [m89].
// ---------------------------------------------------------------------------
__global__ __launch_bounds__(256) void k_lin1(
    const __hip_bfloat16* __restrict__ Am, const __hip_bfloat16* __restrict__ Ax,
    const __hip_bfloat16* __restrict__ Wl, const __hip_bfloat16* __restrict__ Wr,
    const float* __restrict__ bias, __hip_bfloat16* __restrict__ out) {
    const int tid = threadIdx.x;
    const int w  = tid >> 6;
    const int l  = tid & 63;
    const int lr = l & 15;
    const int lk = l >> 4;
    const int j0 = w * 32;
    const int n0 = blockIdx.x * 64;

    bfrag B[2][2][4];
#pragma unroll
    for (int jt = 0; jt < 2; ++jt) {
        const int jrow = j0 + jt * 16 + lr;
#pragma unroll
        for (int ks = 0; ks < 4; ++ks) {
            B[jt][0][ks] = *(const bfrag*)(Wl + jrow * 128 + ks * 32 + lk * 8);
            B[jt][1][ks] = *(const bfrag*)(Wr + jrow * 128 + ks * 32 + lk * 8);
        }
    }
    const float bj0 = bias[j0 + lr];
    const float bj1 = bias[j0 + 16 + lr];

    for (int t = 0; t < 4; ++t) {
        const int rbase = n0 + t * 16;
        int arow = rbase + lr;
        if (arow > N_NODES - 1) arow = N_NODES - 1;
        ffrag acc0 = {0.f, 0.f, 0.f, 0.f};
        ffrag acc1 = {0.f, 0.f, 0.f, 0.f};
#pragma unroll
        for (int ks = 0; ks < 4; ++ks) {
            bfrag am = *(const bfrag*)(Am + (size_t)arow * 128 + ks * 32 + lk * 8);
            bfrag ax = *(const bfrag*)(Ax + (size_t)arow * 128 + ks * 32 + lk * 8);
            acc0 = __builtin_amdgcn_mfma_f32_16x16x32_bf16(am, B[0][0][ks], acc0, 0, 0, 0);
            acc1 = __builtin_amdgcn_mfma_f32_16x16x32_bf16(am, B[1][0][ks], acc1, 0, 0, 0);
            acc0 = __builtin_amdgcn_mfma_f32_16x16x32_bf16(ax, B[0][1][ks], acc0, 0, 0, 0);
            acc1 = __builtin_amdgcn_mfma_f32_16x16x32_bf16(ax, B[1][1][ks], acc1, 0, 0, 0);
        }
#pragma unroll
        for (int r = 0; r < 4; ++r) {
            const int n = rbase + lk * 4 + r;
            if (n < N_NODES) {
                float v0 = fmaxf(acc0[r] + bj0, 0.f);
                unsigned rb0 = tf_word((unsigned)(n * 128 + j0 + lr));
                v0 = (rb0 & 0x80000000u) ? 0.f : (v0 + v0);
                out[(size_t)n * 128 + j0 + lr] = __float2bfloat16(v0);
                float v1 = fmaxf(acc1[r] + bj1, 0.f);
                unsigned rb1 = tf_word((unsigned)(n * 128 + j0 + 16 + lr));
                v1 = (rb1 & 0x80000000u) ? 0.f : (v1 + v1);
                out[(size_t)n * 128 + j0 + 16 + lr] = __float2bfloat16(v1);
            }
        }
    }
}

// ---------------------------------------------------------------------------
// y2[n][j] = h[n]·W2l^T[j]  (no bias), bf16 out [N][64]
// ---------------------------------------------------------------------------
__global__ __launch_bounds__(256) void k_y2(
    const __hip_bfloat16* __restrict__ Ah, const __hip_bfloat16* __restrict__ Wl,
    __hip_bfloat16* __restrict__ y2) {
    const int tid = threadIdx.x;
    const int w  = tid >> 6;
    const int l  = tid & 63;
    const int lr = l & 15;
    const int lk = l >> 4;
    const int j0 = w * 16;
    const int n0 = blockIdx.x * 64;

    bfrag Bl[4];
    const int jrow = j0 + lr;
#pragma unroll
    for (int ks = 0; ks < 4; ++ks)
        Bl[ks] = *(const bfrag*)(Wl + jrow * 128 + ks * 32 + lk * 8);

    for (int t = 0; t < 4; ++t) {
        const int rbase = n0 + t * 16;
        int arow = rbase + lr;
        if (arow > N_NODES - 1) arow = N_NODES - 1;
        ffrag acc = {0.f, 0.f, 0.f, 0.f};
#pragma unroll
        for (int ks = 0; ks < 4; ++ks) {
            bfrag ah = *(const bfrag*)(Ah + (size_t)arow * 128 + ks * 32 + lk * 8);
            acc = __builtin_amdgcn_mfma_f32_16x16x32_bf16(ah, Bl[ks], acc, 0, 0, 0);
        }
#pragma unroll
        for (int r = 0; r < 4; ++r) {
            const int n = rbase + lk * 4 + r;
            if (n < N_NODES)
                y2[(size_t)n * 64 + j0 + lr] = __float2bfloat16(acc[r]);
        }
    }
}

// ---------------------------------------------------------------------------
// Layer 2: out[n][j] = mean_y2[n][j] + b2[j] + h[n]·W2r^T[j], fp32 out [N][64]
// ---------------------------------------------------------------------------
__global__ __launch_bounds__(256) void k_lin2(
    const __hip_bfloat16* __restrict__ M2, const __hip_bfloat16* __restrict__ Ah,
    const __hip_bfloat16* __restrict__ Wr, const float* __restrict__ bias,
    float* __restrict__ out) {
    const int tid = threadIdx.x;
    const int w  = tid >> 6;
    const int l  = tid & 63;
    const int lr = l & 15;
    const int lk = l >> 4;
    const int j0 = w * 16;
    const int n0 = blockIdx.x * 64;

    bfrag Br[4];
    const int jrow = j0 + lr;
#pragma unroll
    for (int ks = 0; ks < 4; ++ks)
        Br[ks] = *(const bfrag*)(Wr + jrow * 128 + ks * 32 + lk * 8);
    const float bj = bias[j0 + lr];

    for (int t = 0; t < 4; ++t) {
        const int rbase = n0 + t * 16;
        int arow = rbase + lr;
        if (arow > N_NODES - 1) arow = N_NODES - 1;
        ffrag acc = {0.f, 0.f, 0.f, 0.f};
#pragma unroll
        for (int ks = 0; ks < 4; ++ks) {
            bfrag ah = *(const bfrag*)(Ah + (size_t)arow * 128 + ks * 32 + lk * 8);
            acc = __builtin_amdgcn_mfma_f32_16x16x32_bf16(ah, Br[ks], acc, 0, 0, 0);
        }
#pragma unroll
        for (int r = 0; r < 4; ++r) {
            const int n = rbase + lk * 4 + r;
            if (n < N_NODES) {
                float m = __bfloat162float(M2[(size_t)n * 64 + j0 + lr]);
                out[(size_t)n * 64 + j0 + lr] = acc[r] + bj + m;
            }
        }
    }
}

// ---------------------------------------------------------------------------
extern "C" void kernel_launch(void* const* d_in, const int* in_sizes, int n_in,
                              void* d_out, int out_size, void* d_ws, size_t ws_size,
                              hipStream_t stream) {
    const float* x   = (const float*)d_in[0];
    const int*   ei  = (const int*)d_in[1];
    const float* W1l = (const float*)d_in[2];
    const float* b1  = (const float*)d_in[3];
    const float* W1r = (const float*)d_in[4];
    const float* W2l = (const float*)d_in[5];
    const float* b2  = (const float*)d_in[6];
    const float* W2r = (const float*)d_in[7];
    float* out = (float*)d_out;

    char* w = (char*)d_ws;
    int* flag   = (int*)w;                       // 64 ints
    int* bincur = flag + 64;                     // 1024 (NBIN used)
    int* binptr = bincur + 1024;                 // 1024
    int* ptr    = binptr + 1024;                 // N+1
    int* adj    = ptr + (N_NODES + 1);           // NE
    size_t foff = (((size_t)(64 + 1024 + 1024 + N_NODES + 1 + NE)) * 4 + 255)
                  & ~(size_t)255;
    __hip_bfloat16* wb    = (__hip_bfloat16*)(w + foff);        // 49152
    __hip_bfloat16* w1lb  = wb;
    __hip_bfloat16* w1rb  = wb + 16384;
    __hip_bfloat16* w2lb  = wb + 32768;
    __hip_bfloat16* w2rb  = wb + 40960;
    __hip_bfloat16* xb    = wb + 49152;                         // N*128
    __hip_bfloat16* meanb = xb + (size_t)N_NODES * 128;         // N*128
    __hip_bfloat16* hb    = meanb + (size_t)N_NODES * 128;      // N*128
    // overlays (regions dead at time of reuse):
    int2* pairs = (int2*)hb;                       // 782*3072*8B=19.2MB < 25.6MB
    __hip_bfloat16* y2b = meanb;                   // [N,64], after lin1
    __hip_bfloat16* m2b = meanb + (size_t)N_NODES * 64;  // [N,64]

    hipMemsetAsync(bincur, 0, 1024 * sizeof(int), stream);

    const int n4 = N_NODES * 128 / 4;
    k_conv<<<(n4 + 255) / 256, 256, 0, stream>>>((const float4*)x, (ushort4*)xb, n4);
    k_wconv<<<192, 256, 0, stream>>>(W1l, W1r, W2l, W2r, wb);

    k_detect<<<1, 256, 0, stream>>>(ei, flag);

    k_binscatter<<<NBLK, 1024, 0, stream>>>(ei, flag, bincur, pairs);
    k_binscan<<<1, 1024, 0, stream>>>(bincur, binptr);
    k_bin2csr<<<NBIN, 256, 0, stream>>>(pairs, binptr, bincur, ptr, adj);

    const int ab = (N_NODES + 3) / 4;            // k_agg: 4 nodes per 256-block
    const int nb = (N_NODES + 63) / 64;
    const int ab2 = (N_NODES + 7) / 8;           // k_agg2: 8 nodes per 256-block

    k_agg<<<ab, 256, 0, stream>>>(xb, ptr, adj, meanb);
    k_lin1<<<nb, 256, 0, stream>>>(meanb, xb, w1lb, w1rb, b1, hb);
    k_y2<<<nb, 256, 0, stream>>>(hb, w2lb, y2b);
    k_agg2<<<ab2, 256, 0, stream>>>(y2b, ptr, adj, m2b);
    k_lin2<<<nb, 256, 0, stream>>>(m2b, hb, w2rb, b2, out);
}

// Round 7
// 249.323 us; speedup vs baseline: 3.0274x; 1.0189x over previous
//
#include <hip/hip_runtime.h>
#include <hip/hip_bf16.h>

#define N_NODES 100000
#define NE      1600000

#define BINSH 7
#define NBIN  782                      // ceil(100000 / 128)
#define BCAP  3072                     // max edges/bin (avg 2046, sigma~45)
#define SEPB  16384                    // edges per binning block
#define NBLK  ((NE + SEPB - 1) / SEPB) // 98
#define NMASKW 200000                  // 12.8M dropout bits / 64

typedef __attribute__((ext_vector_type(8))) short bfrag;   // 8 bf16 (4 VGPR)
typedef __attribute__((ext_vector_type(4))) float ffrag;   // 4 fp32 acc

#define BFLO(u) __uint_as_float((u) << 16)
#define BFHI(u) __uint_as_float((u) & 0xffff0000u)

// ---------------------------------------------------------------------------
// JAX threefry2x32, partitionable path. key=(0,42), counter=(0,f),
// bits = out0 ^ out1, keep <=> top bit == 0.
// ---------------------------------------------------------------------------
__device__ __forceinline__ unsigned tf_rotl(unsigned x, int d) {
    return (x << d) | (x >> (32 - d));
}

__device__ __forceinline__ unsigned tf_word(unsigned f) {
    const unsigned ks0 = 0u;
    const unsigned ks1 = 42u;
    const unsigned ks2 = 0x1BD11BDAu ^ 0u ^ 42u;
    unsigned x0 = 0u + ks0;
    unsigned x1 = f + ks1;
#define TF_RND(r) { x0 += x1; x1 = tf_rotl(x1, r); x1 ^= x0; }
    TF_RND(13) TF_RND(15) TF_RND(26) TF_RND(6)
    x0 += ks1; x1 += ks2 + 1u;
    TF_RND(17) TF_RND(29) TF_RND(16) TF_RND(24)
    x0 += ks2; x1 += ks0 + 2u;
    TF_RND(13) TF_RND(15) TF_RND(26) TF_RND(6)
    x0 += ks0; x1 += ks1 + 3u;
    TF_RND(17) TF_RND(29) TF_RND(16) TF_RND(24)
    x0 += ks1; x1 += ks2 + 4u;
    TF_RND(13) TF_RND(15) TF_RND(26) TF_RND(6)
    x0 += ks2; x1 += ks0 + 5u;
#undef TF_RND
    return x0 ^ x1;
}

__device__ __forceinline__ unsigned short bf_bits(float v) {
    __hip_bfloat16 b = __float2bfloat16(v);
    return *(unsigned short*)&b;
}

// ---------------------------------------------------------------------------
// Dropout keep-mask: wave w, lane i hashes f = w*64+i; ballot packs 64 bits.
// ---------------------------------------------------------------------------
__global__ void k_mask(unsigned long long* __restrict__ km) {
    const int lane = threadIdx.x & 63;
    const int w0 = (blockIdx.x * blockDim.x + threadIdx.x) >> 6;
    const int nw = (gridDim.x * blockDim.x) >> 6;
    for (int widx = w0; widx < NMASKW; widx += nw) {
        unsigned wv = tf_word((unsigned)widx * 64u + (unsigned)lane);
        unsigned long long keep = __ballot(!(wv & 0x80000000u));
        if (lane == 0) km[widx] = keep;
    }
}

// ---------------------------------------------------------------------------
// edge_index dtype probe (int64 => odd 32-bit words all zero)
// ---------------------------------------------------------------------------
__global__ void k_detect(const int* __restrict__ ei, int* __restrict__ flag) {
    __shared__ int nz;
    if (threadIdx.x == 0) nz = 0;
    __syncthreads();
    for (int i = threadIdx.x; i < 1024; i += blockDim.x)
        if (ei[2 * i + 1] != 0) atomicAdd(&nz, 1);
    __syncthreads();
    if (threadIdx.x == 0) *flag = (nz == 0) ? 1 : 0;
}

// ---------------------------------------------------------------------------
// fp32 -> bf16 conversions
// ---------------------------------------------------------------------------
__global__ void k_conv(const float4* __restrict__ in, ushort4* __restrict__ out,
                       int n4) {
    int i = blockIdx.x * blockDim.x + threadIdx.x;
    if (i < n4) {
        float4 v = in[i];
        ushort4 o;
        o.x = bf_bits(v.x);
        o.y = bf_bits(v.y);
        o.z = bf_bits(v.z);
        o.w = bf_bits(v.w);
        out[i] = o;
    }
}

__global__ void k_wconv(const float* __restrict__ a, const float* __restrict__ b,
                        const float* __restrict__ c, const float* __restrict__ d,
                        __hip_bfloat16* __restrict__ o) {
    int i = blockIdx.x * blockDim.x + threadIdx.x;   // 49152 total
    if (i < 16384)      o[i] = __float2bfloat16(a[i]);
    else if (i < 32768) o[i] = __float2bfloat16(b[i - 16384]);
    else if (i < 40960) o[i] = __float2bfloat16(c[i - 32768]);
    else if (i < 49152) o[i] = __float2bfloat16(d[i - 40960]);
}

// ---------------------------------------------------------------------------
// Binned CSR build (single edge pass + per-bin compaction)
// ---------------------------------------------------------------------------
__global__ __launch_bounds__(1024) void k_binscatter(const int* __restrict__ ei,
        const int* __restrict__ flag, int* __restrict__ bincur,
        int2* __restrict__ pairs) {
    __shared__ int h[NBIN];
    __shared__ int lbase[NBIN];
    for (int i = threadIdx.x; i < NBIN; i += 1024) h[i] = 0;
    __syncthreads();
    const int is64 = *flag;
    const int e0 = blockIdx.x * SEPB + threadIdx.x;
    int d[16], s[16];
#pragma unroll
    for (int k = 0; k < 16; ++k) {
        int e = e0 + k * 1024;
        if (e < NE) {
            d[k] = is64 ? ei[2 * (NE + e)] : ei[NE + e];
            s[k] = is64 ? ei[2 * e]        : ei[e];
            atomicAdd(&h[d[k] >> BINSH], 1);
        } else {
            d[k] = -1; s[k] = 0;
        }
    }
    __syncthreads();
    for (int i = threadIdx.x; i < NBIN; i += 1024) {
        int c = h[i];
        lbase[i] = c ? atomicAdd(&bincur[i], c) : 0;
        h[i] = 0;                      // reuse as intra-block rank counter
    }
    __syncthreads();
#pragma unroll
    for (int k = 0; k < 16; ++k) {
        if (d[k] >= 0) {
            int b = d[k] >> BINSH;
            int r = atomicAdd(&h[b], 1);
            pairs[(size_t)b * BCAP + lbase[b] + r] = make_int2(s[k], d[k]);
        }
    }
}

__global__ __launch_bounds__(1024) void k_binscan(const int* __restrict__ bincnt,
        int* __restrict__ binptr) {
    __shared__ int sm[1024];
    const int t = threadIdx.x;
    int v = (t < NBIN) ? bincnt[t] : 0;
    sm[t] = v;
    __syncthreads();
    for (int off = 1; off < 1024; off <<= 1) {
        int u = (t >= off) ? sm[t - off] : 0;
        __syncthreads();
        sm[t] += u;
        __syncthreads();
    }
    if (t < NBIN) binptr[t] = sm[t] - v;   // exclusive
}

__global__ __launch_bounds__(256) void k_bin2csr(const int2* __restrict__ pairs,
        const int* __restrict__ binptr, const int* __restrict__ bincnt,
        int* __restrict__ ptr, int* __restrict__ adj) {
    __shared__ int cnt[128];
    __shared__ int sc[128];
    __shared__ int woff[128];
    const int b = blockIdx.x;
    const int base = binptr[b];
    const int nb = bincnt[b];
    const int2* pb = pairs + (size_t)b * BCAP;
    const int t = threadIdx.x;
    if (t < 128) cnt[t] = 0;
    __syncthreads();
    for (int i = t; i < nb; i += 256)
        atomicAdd(&cnt[pb[i].y & 127], 1);
    __syncthreads();
    if (t < 128) sc[t] = cnt[t];
    __syncthreads();
    for (int o = 1; o < 128; o <<= 1) {
        int u = 0;
        if (t < 128 && t >= o) u = sc[t - o];
        __syncthreads();
        if (t < 128) sc[t] += u;
        __syncthreads();
    }
    if (t < 128) {
        int ex = sc[t] - cnt[t];
        int node = b * 128 + t;
        if (node <= N_NODES) ptr[node] = base + ex;
        woff[t] = ex;
    }
    __syncthreads();
    for (int i = t; i < nb; i += 256) {
        int2 p = pb[i];
        int r = atomicAdd(&woff[p.y & 127], 1);
        adj[base + r] = p.x;
    }
}

// ---------------------------------------------------------------------------
// bf16 pull aggregation, 128-dim: one wave per node, unroll 8
// ---------------------------------------------------------------------------
__global__ void k_agg(const __hip_bfloat16* __restrict__ feat,
                      const int* __restrict__ ptr, const int* __restrict__ adj,
                      __hip_bfloat16* __restrict__ mean) {
    const int wid = (blockIdx.x * blockDim.x + threadIdx.x) >> 6;
    const int lane = threadIdx.x & 63;
    if (wid >= N_NODES) return;
    const int p0 = ptr[wid], p1 = ptr[wid + 1];
    float a0 = 0.f, b0 = 0.f, a1 = 0.f, b1 = 0.f;
    float a2 = 0.f, b2 = 0.f, a3 = 0.f, b3 = 0.f;
    int p = p0;
    for (; p + 7 < p1; p += 8) {
        int s0 = adj[p],     s1 = adj[p + 1], s2 = adj[p + 2], s3 = adj[p + 3];
        int s4 = adj[p + 4], s5 = adj[p + 5], s6 = adj[p + 6], s7 = adj[p + 7];
        unsigned u0 = *(const unsigned*)(feat + (size_t)s0 * 128 + lane * 2);
        unsigned u1 = *(const unsigned*)(feat + (size_t)s1 * 128 + lane * 2);
        unsigned u2 = *(const unsigned*)(feat + (size_t)s2 * 128 + lane * 2);
        unsigned u3 = *(const unsigned*)(feat + (size_t)s3 * 128 + lane * 2);
        unsigned u4 = *(const unsigned*)(feat + (size_t)s4 * 128 + lane * 2);
        unsigned u5 = *(const unsigned*)(feat + (size_t)s5 * 128 + lane * 2);
        unsigned u6 = *(const unsigned*)(feat + (size_t)s6 * 128 + lane * 2);
        unsigned u7 = *(const unsigned*)(feat + (size_t)s7 * 128 + lane * 2);
        a0 += BFLO(u0); b0 += BFHI(u0); a1 += BFLO(u1); b1 += BFHI(u1);
        a2 += BFLO(u2); b2 += BFHI(u2); a3 += BFLO(u3); b3 += BFHI(u3);
        a0 += BFLO(u4); b0 += BFHI(u4); a1 += BFLO(u5); b1 += BFHI(u5);
        a2 += BFLO(u6); b2 += BFHI(u6); a3 += BFLO(u7); b3 += BFHI(u7);
    }
    for (; p + 3 < p1; p += 4) {
        int s0 = adj[p], s1 = adj[p + 1], s2 = adj[p + 2], s3 = adj[p + 3];
        unsigned u0 = *(const unsigned*)(feat + (size_t)s0 * 128 + lane * 2);
        unsigned u1 = *(const unsigned*)(feat + (size_t)s1 * 128 + lane * 2);
        unsigned u2 = *(const unsigned*)(feat + (size_t)s2 * 128 + lane * 2);
        unsigned u3 = *(const unsigned*)(feat + (size_t)s3 * 128 + lane * 2);
        a0 += BFLO(u0); b0 += BFHI(u0); a1 += BFLO(u1); b1 += BFHI(u1);
        a2 += BFLO(u2); b2 += BFHI(u2); a3 += BFLO(u3); b3 += BFHI(u3);
    }
    for (; p < p1; ++p) {
        int s0 = adj[p];
        unsigned u0 = *(const unsigned*)(feat + (size_t)s0 * 128 + lane * 2);
        a0 += BFLO(u0); b0 += BFHI(u0);
    }
    const float inv = 1.0f / (float)max(p1 - p0, 1);
    float m0 = ((a0 + a1) + (a2 + a3)) * inv;
    float m1 = ((b0 + b1) + (b2 + b3)) * inv;
    unsigned o = ((unsigned)bf_bits(m1) << 16) | (unsigned)bf_bits(m0);
    *(unsigned*)(mean + (size_t)wid * 128 + lane * 2) = o;
}

// ---------------------------------------------------------------------------
// Fused layer1 + layer2-projections:
//   h = dropout(relu(mean1·W1l^T + x·W1r^T + b1))   (LDS only)
//   y2 = h·W2l^T (bf16, for layer-2 mean gather)
//   z  = h·W2r^T + b2  -> written to d_out (agg2f adds mean_y2 later)
// MFMA 16x16x32 bf16; C/D: col=lane&15, row=(lane>>4)*4+reg  [m89].
// ---------------------------------------------------------------------------
__global__ __launch_bounds__(256) void k_lin1f(
    const __hip_bfloat16* __restrict__ Am, const __hip_bfloat16* __restrict__ Ax,
    const __hip_bfloat16* __restrict__ W1l, const __hip_bfloat16* __restrict__ W1r,
    const float* __restrict__ b1,
    const __hip_bfloat16* __restrict__ W2l, const __hip_bfloat16* __restrict__ W2r,
    const float* __restrict__ b2,
    const unsigned long long* __restrict__ kmask,
    __hip_bfloat16* __restrict__ y2, float* __restrict__ zout) {
    __shared__ __align__(16) __hip_bfloat16 hs[64][136];   // +8 pad: bank spread
    const int tid = threadIdx.x;
    const int w  = tid >> 6;
    const int l  = tid & 63;
    const int lr = l & 15;
    const int lk = l >> 4;
    const int j0 = w * 32;           // phase-1 h-cols owned by this wave
    const int j2 = w * 16 + lr;      // phase-2 out-col
    const int n0 = blockIdx.x * 64;

    bfrag B1[2][2][4];
#pragma unroll
    for (int jt = 0; jt < 2; ++jt) {
        const int jrow = j0 + jt * 16 + lr;
#pragma unroll
        for (int ks = 0; ks < 4; ++ks) {
            B1[jt][0][ks] = *(const bfrag*)(W1l + jrow * 128 + ks * 32 + lk * 8);
            B1[jt][1][ks] = *(const bfrag*)(W1r + jrow * 128 + ks * 32 + lk * 8);
        }
    }
    bfrag Bl2[4], Br2[4];
#pragma unroll
    for (int ks = 0; ks < 4; ++ks) {
        Bl2[ks] = *(const bfrag*)(W2l + j2 * 128 + ks * 32 + lk * 8);
        Br2[ks] = *(const bfrag*)(W2r + j2 * 128 + ks * 32 + lk * 8);
    }
    const float bj0 = b1[j0 + lr];
    const float bj1 = b1[j0 + 16 + lr];
    const float bj2 = b2[j2];

    // ---- phase 1: h tile -> LDS -------------------------------------------
    for (int t = 0; t < 4; ++t) {
        const int rbase = n0 + t * 16;
        int arow = rbase + lr;
        if (arow > N_NODES - 1) arow = N_NODES - 1;
        ffrag acc0 = {0.f, 0.f, 0.f, 0.f};
        ffrag acc1 = {0.f, 0.f, 0.f, 0.f};
#pragma unroll
        for (int ks = 0; ks < 4; ++ks) {
            bfrag am = *(const bfrag*)(Am + (size_t)arow * 128 + ks * 32 + lk * 8);
            bfrag ax = *(const bfrag*)(Ax + (size_t)arow * 128 + ks * 32 + lk * 8);
            acc0 = __builtin_amdgcn_mfma_f32_16x16x32_bf16(am, B1[0][0][ks], acc0, 0, 0, 0);
            acc1 = __builtin_amdgcn_mfma_f32_16x16x32_bf16(am, B1[1][0][ks], acc1, 0, 0, 0);
            acc0 = __builtin_amdgcn_mfma_f32_16x16x32_bf16(ax, B1[0][1][ks], acc0, 0, 0, 0);
            acc1 = __builtin_amdgcn_mfma_f32_16x16x32_bf16(ax, B1[1][1][ks], acc1, 0, 0, 0);
        }
#pragma unroll
        for (int r = 0; r < 4; ++r) {
            const int n = rbase + lk * 4 + r;
            const int lrow = t * 16 + lk * 4 + r;
            const int nm = (n < N_NODES) ? n : (N_NODES - 1);
            const unsigned long long km = kmask[nm * 2 + (j0 >> 6)];
            float v0 = fmaxf(acc0[r] + bj0, 0.f);
            v0 = ((km >> ((j0 + lr) & 63)) & 1ull) ? (v0 + v0) : 0.f;
            hs[lrow][j0 + lr] = __float2bfloat16(v0);
            float v1 = fmaxf(acc1[r] + bj1, 0.f);
            v1 = ((km >> ((j0 + 16 + lr) & 63)) & 1ull) ? (v1 + v1) : 0.f;
            hs[lrow][j0 + 16 + lr] = __float2bfloat16(v1);
        }
    }
    __syncthreads();

    // ---- phase 2: y2 = h·W2l^T, z = h·W2r^T + b2 --------------------------
    for (int t = 0; t < 4; ++t) {
        ffrag accY = {0.f, 0.f, 0.f, 0.f};
        ffrag accZ = {0.f, 0.f, 0.f, 0.f};
#pragma unroll
        for (int ks = 0; ks < 4; ++ks) {
            bfrag ah = *(const bfrag*)&hs[t * 16 + lr][ks * 32 + lk * 8];
            accY = __builtin_amdgcn_mfma_f32_16x16x32_bf16(ah, Bl2[ks], accY, 0, 0, 0);
            accZ = __builtin_amdgcn_mfma_f32_16x16x32_bf16(ah, Br2[ks], accZ, 0, 0, 0);
        }
#pragma unroll
        for (int r = 0; r < 4; ++r) {
            const int n = n0 + t * 16 + lk * 4 + r;
            if (n < N_NODES) {
                y2[(size_t)n * 64 + j2]   = __float2bfloat16(accY[r]);
                zout[(size_t)n * 64 + j2] = accZ[r] + bj2;
            }
        }
    }
}

// ---------------------------------------------------------------------------
// Layer-2 gather+finish: out[n][:] = z[n][:] + mean_{nbr} y2[nbr][:]
// 64-dim rows, 32 lanes per node, 2 nodes/wave, unroll 8
// ---------------------------------------------------------------------------
__global__ void k_agg2f(const __hip_bfloat16* __restrict__ feat,
                        const int* __restrict__ ptr, const int* __restrict__ adj,
                        float* __restrict__ out) {
    const int node = (blockIdx.x * blockDim.x + threadIdx.x) >> 5;
    const int sl = threadIdx.x & 31;
    if (node >= N_NODES) return;
    const int p0 = ptr[node], p1 = ptr[node + 1];
    float a0 = 0.f, b0 = 0.f, a1 = 0.f, b1 = 0.f;
    float a2 = 0.f, b2 = 0.f, a3 = 0.f, b3 = 0.f;
    int p = p0;
    for (; p + 7 < p1; p += 8) {
        int s0 = adj[p],     s1 = adj[p + 1], s2 = adj[p + 2], s3 = adj[p + 3];
        int s4 = adj[p + 4], s5 = adj[p + 5], s6 = adj[p + 6], s7 = adj[p + 7];
        unsigned u0 = *(const unsigned*)(feat + (size_t)s0 * 64 + sl * 2);
        unsigned u1 = *(const unsigned*)(feat + (size_t)s1 * 64 + sl * 2);
        unsigned u2 = *(const unsigned*)(feat + (size_t)s2 * 64 + sl * 2);
        unsigned u3 = *(const unsigned*)(feat + (size_t)s3 * 64 + sl * 2);
        unsigned u4 = *(const unsigned*)(feat + (size_t)s4 * 64 + sl * 2);
        unsigned u5 = *(const unsigned*)(feat + (size_t)s5 * 64 + sl * 2);
        unsigned u6 = *(const unsigned*)(feat + (size_t)s6 * 64 + sl * 2);
        unsigned u7 = *(const unsigned*)(feat + (size_t)s7 * 64 + sl * 2);
        a0 += BFLO(u0); b0 += BFHI(u0); a1 += BFLO(u1); b1 += BFHI(u1);
        a2 += BFLO(u2); b2 += BFHI(u2); a3 += BFLO(u3); b3 += BFHI(u3);
        a0 += BFLO(u4); b0 += BFHI(u4); a1 += BFLO(u5); b1 += BFHI(u5);
        a2 += BFLO(u6); b2 += BFHI(u6); a3 += BFLO(u7); b3 += BFHI(u7);
    }
    for (; p + 3 < p1; p += 4) {
        int s0 = adj[p], s1 = adj[p + 1], s2 = adj[p + 2], s3 = adj[p + 3];
        unsigned u0 = *(const unsigned*)(feat + (size_t)s0 * 64 + sl * 2);
        unsigned u1 = *(const unsigned*)(feat + (size_t)s1 * 64 + sl * 2);
        unsigned u2 = *(const unsigned*)(feat + (size_t)s2 * 64 + sl * 2);
        unsigned u3 = *(const unsigned*)(feat + (size_t)s3 * 64 + sl * 2);
        a0 += BFLO(u0); b0 += BFHI(u0); a1 += BFLO(u1); b1 += BFHI(u1);
        a2 += BFLO(u2); b2 += BFHI(u2); a3 += BFLO(u3); b3 += BFHI(u3);
    }
    for (; p < p1; ++p) {
        int s0 = adj[p];
        unsigned u0 = *(const unsigned*)(feat + (size_t)s0 * 64 + sl * 2);
        a0 += BFLO(u0); b0 += BFHI(u0);
    }
    const float inv = 1.0f / (float)max(p1 - p0, 1);
    float m0 = ((a0 + a1) + (a2 + a3)) * inv;
    float m1 = ((b0 + b1) + (b2 + b3)) * inv;
    float2 z = *(const float2*)(out + (size_t)node * 64 + sl * 2);
    float2 o;
    o.x = z.x + m0;
    o.y = z.y + m1;
    *(float2*)(out + (size_t)node * 64 + sl * 2) = o;
}

// ---------------------------------------------------------------------------
extern "C" void kernel_launch(void* const* d_in, const int* in_sizes, int n_in,
                              void* d_out, int out_size, void* d_ws, size_t ws_size,
                              hipStream_t stream) {
    const float* x   = (const float*)d_in[0];
    const int*   ei  = (const int*)d_in[1];
    const float* W1l = (const float*)d_in[2];
    const float* b1  = (const float*)d_in[3];
    const float* W1r = (const float*)d_in[4];
    const float* W2l = (const float*)d_in[5];
    const float* b2  = (const float*)d_in[6];
    const float* W2r = (const float*)d_in[7];
    float* out = (float*)d_out;

    char* w = (char*)d_ws;
    int* flag   = (int*)w;                       // 64 ints
    int* bincur = flag + 64;                     // 1024 (NBIN used)
    int* binptr = bincur + 1024;                 // 1024
    int* ptr    = binptr + 1024;                 // N+1
    int* adj    = ptr + (N_NODES + 1);           // NE
    size_t koff = (((size_t)(64 + 1024 + 1024 + N_NODES + 1 + NE)) * 4 + 255)
                  & ~(size_t)255;
    unsigned long long* kmask = (unsigned long long*)(w + koff);  // 200000 ull
    size_t foff = (koff + (size_t)NMASKW * 8 + 255) & ~(size_t)255;
    __hip_bfloat16* wb    = (__hip_bfloat16*)(w + foff);        // 49152
    __hip_bfloat16* w1lb  = wb;
    __hip_bfloat16* w1rb  = wb + 16384;
    __hip_bfloat16* w2lb  = wb + 32768;
    __hip_bfloat16* w2rb  = wb + 40960;
    __hip_bfloat16* xb    = wb + 49152;                         // N*128
    __hip_bfloat16* meanb = xb + (size_t)N_NODES * 128;         // N*128
    char* pregion = (char*)(meanb + (size_t)N_NODES * 128);
    int2* pairs = (int2*)pregion;                 // 19.2 MB, dead after bin2csr
    __hip_bfloat16* y2b = (__hip_bfloat16*)pregion;  // [N,64] overlay

    hipMemsetAsync(bincur, 0, 1024 * sizeof(int), stream);

    const int n4 = N_NODES * 128 / 4;
    k_conv<<<(n4 + 255) / 256, 256, 0, stream>>>((const float4*)x, (ushort4*)xb, n4);
    k_wconv<<<192, 256, 0, stream>>>(W1l, W1r, W2l, W2r, wb);
    k_detect<<<1, 256, 0, stream>>>(ei, flag);
    k_mask<<<1024, 256, 0, stream>>>(kmask);

    k_binscatter<<<NBLK, 1024, 0, stream>>>(ei, flag, bincur, pairs);
    k_binscan<<<1, 1024, 0, stream>>>(bincur, binptr);
    k_bin2csr<<<NBIN, 256, 0, stream>>>(pairs, binptr, bincur, ptr, adj);

    const int ab  = (N_NODES + 3) / 4;           // k_agg:   4 nodes / 256-block
    const int nb  = (N_NODES + 63) / 64;
    const int ab2 = (N_NODES + 7) / 8;           // k_agg2f: 8 nodes / 256-block

    k_agg<<<ab, 256, 0, stream>>>(xb, ptr, adj, meanb);
    k_lin1f<<<nb, 256, 0, stream>>>(meanb, xb, w1lb, w1rb, b1,
                                    w2lb, w2rb, b2, kmask, y2b, out);
    k_agg2f<<<ab2, 256, 0, stream>>>(y2b, ptr, adj, out);
}

// Round 8
// 243.228 us; speedup vs baseline: 3.1032x; 1.0251x over previous
//
#include <hip/hip_runtime.h>
#include <hip/hip_bf16.h>

#define N_NODES 100000
#define NE      1600000

#define BINSH 7
#define NBIN  782                      // ceil(100000 / 128)
#define BCAP  3072                     // max edges/bin (avg 2046, sigma~45)
#define SEPB  16384                    // edges per binning block
#define NBLK  ((NE + SEPB - 1) / SEPB) // 98
#define NMASKW 200000                  // 12.8M dropout bits / 64

typedef __attribute__((ext_vector_type(8))) short bfrag;   // 8 bf16 (4 VGPR)
typedef __attribute__((ext_vector_type(4))) float ffrag;   // 4 fp32 acc

#define BFLO(u) __uint_as_float((u) << 16)
#define BFHI(u) __uint_as_float((u) & 0xffff0000u)

// ---------------------------------------------------------------------------
// JAX threefry2x32, partitionable path. key=(0,42), counter=(0,f),
// bits = out0 ^ out1, keep <=> top bit == 0.
// ---------------------------------------------------------------------------
__device__ __forceinline__ unsigned tf_rotl(unsigned x, int d) {
    return (x << d) | (x >> (32 - d));
}

__device__ __forceinline__ unsigned tf_word(unsigned f) {
    const unsigned ks0 = 0u;
    const unsigned ks1 = 42u;
    const unsigned ks2 = 0x1BD11BDAu ^ 0u ^ 42u;
    unsigned x0 = 0u + ks0;
    unsigned x1 = f + ks1;
#define TF_RND(r) { x0 += x1; x1 = tf_rotl(x1, r); x1 ^= x0; }
    TF_RND(13) TF_RND(15) TF_RND(26) TF_RND(6)
    x0 += ks1; x1 += ks2 + 1u;
    TF_RND(17) TF_RND(29) TF_RND(16) TF_RND(24)
    x0 += ks2; x1 += ks0 + 2u;
    TF_RND(13) TF_RND(15) TF_RND(26) TF_RND(6)
    x0 += ks0; x1 += ks1 + 3u;
    TF_RND(17) TF_RND(29) TF_RND(16) TF_RND(24)
    x0 += ks1; x1 += ks2 + 4u;
    TF_RND(13) TF_RND(15) TF_RND(26) TF_RND(6)
    x0 += ks2; x1 += ks0 + 5u;
#undef TF_RND
    return x0 ^ x1;
}

__device__ __forceinline__ unsigned short bf_bits(float v) {
    __hip_bfloat16 b = __float2bfloat16(v);
    return *(unsigned short*)&b;
}

// ---------------------------------------------------------------------------
// Dropout keep-mask: wave w, lane i hashes f = w*64+i; ballot packs 64 bits.
// ---------------------------------------------------------------------------
__global__ void k_mask(unsigned long long* __restrict__ km) {
    const int lane = threadIdx.x & 63;
    const int w0 = (blockIdx.x * blockDim.x + threadIdx.x) >> 6;
    const int nw = (gridDim.x * blockDim.x) >> 6;
    for (int widx = w0; widx < NMASKW; widx += nw) {
        unsigned wv = tf_word((unsigned)widx * 64u + (unsigned)lane);
        unsigned long long keep = __ballot(!(wv & 0x80000000u));
        if (lane == 0) km[widx] = keep;
    }
}

// ---------------------------------------------------------------------------
// edge_index dtype probe (int64 => odd 32-bit words all zero) + bincur zero
// ---------------------------------------------------------------------------
__global__ void k_detect(const int* __restrict__ ei, int* __restrict__ flag,
                         int* __restrict__ bincur) {
    __shared__ int nz;
    if (threadIdx.x == 0) nz = 0;
    __syncthreads();
    for (int i = threadIdx.x; i < 1024; i += blockDim.x) {
        if (ei[2 * i + 1] != 0) atomicAdd(&nz, 1);
        bincur[i] = 0;
    }
    __syncthreads();
    if (threadIdx.x == 0) *flag = (nz == 0) ? 1 : 0;
}

// ---------------------------------------------------------------------------
// fp32 -> bf16 conversions
// ---------------------------------------------------------------------------
__global__ void k_conv(const float4* __restrict__ in, ushort4* __restrict__ out,
                       int n4) {
    int i = blockIdx.x * blockDim.x + threadIdx.x;
    if (i < n4) {
        float4 v = in[i];
        ushort4 o;
        o.x = bf_bits(v.x);
        o.y = bf_bits(v.y);
        o.z = bf_bits(v.z);
        o.w = bf_bits(v.w);
        out[i] = o;
    }
}

__global__ void k_wconv(const float* __restrict__ a, const float* __restrict__ b,
                        const float* __restrict__ c, const float* __restrict__ d,
                        __hip_bfloat16* __restrict__ o) {
    int i = blockIdx.x * blockDim.x + threadIdx.x;   // 49152 total
    if (i < 16384)      o[i] = __float2bfloat16(a[i]);
    else if (i < 32768) o[i] = __float2bfloat16(b[i - 16384]);
    else if (i < 40960) o[i] = __float2bfloat16(c[i - 32768]);
    else if (i < 49152) o[i] = __float2bfloat16(d[i - 40960]);
}

// ---------------------------------------------------------------------------
// Binned CSR build. pairs packed: (dstlocal 7b << 17) | src 17b.
// ---------------------------------------------------------------------------
__global__ __launch_bounds__(1024) void k_binscatter(const int* __restrict__ ei,
        const int* __restrict__ flag, int* __restrict__ bincur,
        int* __restrict__ pairs) {
    __shared__ int h[NBIN];
    __shared__ int lbase[NBIN];
    for (int i = threadIdx.x; i < NBIN; i += 1024) h[i] = 0;
    __syncthreads();
    const int is64 = *flag;
    const int e0 = blockIdx.x * SEPB + threadIdx.x;
    int d[16], s[16];
#pragma unroll
    for (int k = 0; k < 16; ++k) {
        int e = e0 + k * 1024;
        if (e < NE) {
            d[k] = is64 ? ei[2 * (NE + e)] : ei[NE + e];
            s[k] = is64 ? ei[2 * e]        : ei[e];
            atomicAdd(&h[d[k] >> BINSH], 1);
        } else {
            d[k] = -1; s[k] = 0;
        }
    }
    __syncthreads();
    for (int i = threadIdx.x; i < NBIN; i += 1024) {
        int c = h[i];
        lbase[i] = c ? atomicAdd(&bincur[i], c) : 0;
        h[i] = 0;                      // reuse as intra-block rank counter
    }
    __syncthreads();
#pragma unroll
    for (int k = 0; k < 16; ++k) {
        if (d[k] >= 0) {
            int b = d[k] >> BINSH;
            int r = atomicAdd(&h[b], 1);
            pairs[(size_t)b * BCAP + lbase[b] + r] =
                ((d[k] & 127) << 17) | s[k];
        }
    }
}

__global__ __launch_bounds__(256) void k_bin2csr(const int* __restrict__ pairs,
        const int* __restrict__ bincnt, int* __restrict__ ptr,
        int* __restrict__ adj) {
    __shared__ int red[256];
    __shared__ int cnt[128];
    __shared__ int sc[128];
    __shared__ int woff[128];
    const int b = blockIdx.x;
    const int t = threadIdx.x;
    // base = sum of bincnt[0..b)
    int s = 0;
    for (int i = t; i < b; i += 256) s += bincnt[i];
    red[t] = s;
    __syncthreads();
    for (int o = 128; o > 0; o >>= 1) {
        if (t < o) red[t] += red[t + o];
        __syncthreads();
    }
    const int base = red[0];
    const int nb = bincnt[b];
    const int* pb = pairs + (size_t)b * BCAP;
    if (t < 128) cnt[t] = 0;
    __syncthreads();
    for (int i = t; i < nb; i += 256)
        atomicAdd(&cnt[(pb[i] >> 17) & 127], 1);
    __syncthreads();
    if (t < 128) sc[t] = cnt[t];
    __syncthreads();
    for (int o = 1; o < 128; o <<= 1) {
        int u = 0;
        if (t < 128 && t >= o) u = sc[t - o];
        __syncthreads();
        if (t < 128) sc[t] += u;
        __syncthreads();
    }
    if (t < 128) {
        int ex = sc[t] - cnt[t];
        int node = b * 128 + t;
        if (node <= N_NODES) ptr[node] = base + ex;
        woff[t] = ex;
    }
    __syncthreads();
    for (int i = t; i < nb; i += 256) {
        int pk = pb[i];
        int r = atomicAdd(&woff[(pk >> 17) & 127], 1);
        adj[base + r] = pk & 0x1FFFF;
    }
}

// ---------------------------------------------------------------------------
// bf16 pull aggregation, 128-dim: one wave per node, 2 edges per load issue
// (half-wave x 8B), up to 16 edges in flight; shfl_xor(32) combine.
// ---------------------------------------------------------------------------
__global__ void k_agg(const __hip_bfloat16* __restrict__ feat,
                      const int* __restrict__ ptr, const int* __restrict__ adj,
                      __hip_bfloat16* __restrict__ mean) {
    const int wid = (blockIdx.x * blockDim.x + threadIdx.x) >> 6;
    const int lane = threadIdx.x & 63;
    if (wid >= N_NODES) return;
    const int p0 = ptr[wid], p1 = ptr[wid + 1];
    const int half = lane >> 5;        // edge parity within a pair
    const size_t coff = (size_t)(lane & 31) * 4;   // cols coff..coff+3
    float c0 = 0.f, c1 = 0.f, c2 = 0.f, c3 = 0.f;
    float d0 = 0.f, d1 = 0.f, d2 = 0.f, d3 = 0.f;
    int p = p0;
    for (; p + 15 < p1; p += 16) {     // 8 loads, 16 edges
        int s[8];
#pragma unroll
        for (int k = 0; k < 8; ++k) s[k] = adj[p + 2 * k + half];
#pragma unroll
        for (int k = 0; k < 8; ++k) {
            uint2 u = *(const uint2*)(feat + (size_t)s[k] * 128 + coff);
            if (k & 1) { d0 += BFLO(u.x); d1 += BFHI(u.x); d2 += BFLO(u.y); d3 += BFHI(u.y); }
            else       { c0 += BFLO(u.x); c1 += BFHI(u.x); c2 += BFLO(u.y); c3 += BFHI(u.y); }
        }
    }
    for (; p + 7 < p1; p += 8) {       // 4 loads, 8 edges
        int s[4];
#pragma unroll
        for (int k = 0; k < 4; ++k) s[k] = adj[p + 2 * k + half];
#pragma unroll
        for (int k = 0; k < 4; ++k) {
            uint2 u = *(const uint2*)(feat + (size_t)s[k] * 128 + coff);
            if (k & 1) { d0 += BFLO(u.x); d1 += BFHI(u.x); d2 += BFLO(u.y); d3 += BFHI(u.y); }
            else       { c0 += BFLO(u.x); c1 += BFHI(u.x); c2 += BFLO(u.y); c3 += BFHI(u.y); }
        }
    }
    for (; p + 1 < p1; p += 2) {       // 1 load, 2 edges
        int s = adj[p + half];
        uint2 u = *(const uint2*)(feat + (size_t)s * 128 + coff);
        c0 += BFLO(u.x); c1 += BFHI(u.x); c2 += BFLO(u.y); c3 += BFHI(u.y);
    }
    if (p < p1 && half == 0) {         // odd tail: half 0 only
        int s = adj[p];
        uint2 u = *(const uint2*)(feat + (size_t)s * 128 + coff);
        c0 += BFLO(u.x); c1 += BFHI(u.x); c2 += BFLO(u.y); c3 += BFHI(u.y);
    }
    c0 += d0; c1 += d1; c2 += d2; c3 += d3;
    c0 += __shfl_xor(c0, 32);
    c1 += __shfl_xor(c1, 32);
    c2 += __shfl_xor(c2, 32);
    c3 += __shfl_xor(c3, 32);
    if (half == 0) {
        const float inv = 1.0f / (float)max(p1 - p0, 1);
        uint2 o;
        o.x = ((unsigned)bf_bits(c1 * inv) << 16) | (unsigned)bf_bits(c0 * inv);
        o.y = ((unsigned)bf_bits(c3 * inv) << 16) | (unsigned)bf_bits(c2 * inv);
        *(uint2*)(mean + (size_t)wid * 128 + coff) = o;
    }
}

// ---------------------------------------------------------------------------
// Fused layer1 + layer2-projections:
//   h = dropout(relu(mean1·W1l^T + x·W1r^T + b1))   (LDS only)
//   y2 = h·W2l^T (bf16, for layer-2 mean gather)
//   z  = h·W2r^T + b2  -> written to d_out (agg2f adds mean_y2 later)
// MFMA 16x16x32 bf16; C/D: col=lane&15, row=(lane>>4)*4+reg  [m89].
// ---------------------------------------------------------------------------
__global__ __launch_bounds__(256) void k_lin1f(
    const __hip_bfloat16* __restrict__ Am, const __hip_bfloat16* __restrict__ Ax,
    const __hip_bfloat16* __restrict__ W1l, const __hip_bfloat16* __restrict__ W1r,
    const float* __restrict__ b1,
    const __hip_bfloat16* __restrict__ W2l, const __hip_bfloat16* __restrict__ W2r,
    const float* __restrict__ b2,
    const unsigned long long* __restrict__ kmask,
    __hip_bfloat16* __restrict__ y2, float* __restrict__ zout) {
    __shared__ __align__(16) __hip_bfloat16 hs[64][136];   // +8 pad: bank spread
    const int tid = threadIdx.x;
    const int w  = tid >> 6;
    const int l  = tid & 63;
    const int lr = l & 15;
    const int lk = l >> 4;
    const int j0 = w * 32;           // phase-1 h-cols owned by this wave
    const int j2 = w * 16 + lr;      // phase-2 out-col
    const int n0 = blockIdx.x * 64;

    bfrag B1[2][2][4];
#pragma unroll
    for (int jt = 0; jt < 2; ++jt) {
        const int jrow = j0 + jt * 16 + lr;
#pragma unroll
        for (int ks = 0; ks < 4; ++ks) {
            B1[jt][0][ks] = *(const bfrag*)(W1l + jrow * 128 + ks * 32 + lk * 8);
            B1[jt][1][ks] = *(const bfrag*)(W1r + jrow * 128 + ks * 32 + lk * 8);
        }
    }
    bfrag Bl2[4], Br2[4];
#pragma unroll
    for (int ks = 0; ks < 4; ++ks) {
        Bl2[ks] = *(const bfrag*)(W2l + j2 * 128 + ks * 32 + lk * 8);
        Br2[ks] = *(const bfrag*)(W2r + j2 * 128 + ks * 32 + lk * 8);
    }
    const float bj0 = b1[j0 + lr];
    const float bj1 = b1[j0 + 16 + lr];
    const float bj2 = b2[j2];

    // ---- phase 1: h tile -> LDS -------------------------------------------
    for (int t = 0; t < 4; ++t) {
        const int rbase = n0 + t * 16;
        int arow = rbase + lr;
        if (arow > N_NODES - 1) arow = N_NODES - 1;
        ffrag acc0 = {0.f, 0.f, 0.f, 0.f};
        ffrag acc1 = {0.f, 0.f, 0.f, 0.f};
#pragma unroll
        for (int ks = 0; ks < 4; ++ks) {
            bfrag am = *(const bfrag*)(Am + (size_t)arow * 128 + ks * 32 + lk * 8);
            bfrag ax = *(const bfrag*)(Ax + (size_t)arow * 128 + ks * 32 + lk * 8);
            acc0 = __builtin_amdgcn_mfma_f32_16x16x32_bf16(am, B1[0][0][ks], acc0, 0, 0, 0);
            acc1 = __builtin_amdgcn_mfma_f32_16x16x32_bf16(am, B1[1][0][ks], acc1, 0, 0, 0);
            acc0 = __builtin_amdgcn_mfma_f32_16x16x32_bf16(ax, B1[0][1][ks], acc0, 0, 0, 0);
            acc1 = __builtin_amdgcn_mfma_f32_16x16x32_bf16(ax, B1[1][1][ks], acc1, 0, 0, 0);
        }
#pragma unroll
        for (int r = 0; r < 4; ++r) {
            const int n = rbase + lk * 4 + r;
            const int lrow = t * 16 + lk * 4 + r;
            const int nm = (n < N_NODES) ? n : (N_NODES - 1);
            const unsigned long long km = kmask[nm * 2 + (j0 >> 6)];
            float v0 = fmaxf(acc0[r] + bj0, 0.f);
            v0 = ((km >> ((j0 + lr) & 63)) & 1ull) ? (v0 + v0) : 0.f;
            hs[lrow][j0 + lr] = __float2bfloat16(v0);
            float v1 = fmaxf(acc1[r] + bj1, 0.f);
            v1 = ((km >> ((j0 + 16 + lr) & 63)) & 1ull) ? (v1 + v1) : 0.f;
            hs[lrow][j0 + 16 + lr] = __float2bfloat16(v1);
        }
    }
    __syncthreads();

    // ---- phase 2: y2 = h·W2l^T, z = h·W2r^T + b2 --------------------------
    for (int t = 0; t < 4; ++t) {
        ffrag accY = {0.f, 0.f, 0.f, 0.f};
        ffrag accZ = {0.f, 0.f, 0.f, 0.f};
#pragma unroll
        for (int ks = 0; ks < 4; ++ks) {
            bfrag ah = *(const bfrag*)&hs[t * 16 + lr][ks * 32 + lk * 8];
            accY = __builtin_amdgcn_mfma_f32_16x16x32_bf16(ah, Bl2[ks], accY, 0, 0, 0);
            accZ = __builtin_amdgcn_mfma_f32_16x16x32_bf16(ah, Br2[ks], accZ, 0, 0, 0);
        }
#pragma unroll
        for (int r = 0; r < 4; ++r) {
            const int n = n0 + t * 16 + lk * 4 + r;
            if (n < N_NODES) {
                y2[(size_t)n * 64 + j2]   = __float2bfloat16(accY[r]);
                zout[(size_t)n * 64 + j2] = accZ[r] + bj2;
            }
        }
    }
}

// ---------------------------------------------------------------------------
// Layer-2 gather+finish: out[n][:] = z[n][:] + mean_{nbr} y2[nbr][:]
// 64-dim rows, 2 nodes/wave; 2 edges per load issue (16-lane x 8B);
// shfl_xor(16) combine.
// ---------------------------------------------------------------------------
__global__ void k_agg2f(const __hip_bfloat16* __restrict__ feat,
                        const int* __restrict__ ptr, const int* __restrict__ adj,
                        float* __restrict__ out) {
    const int node = (blockIdx.x * blockDim.x + threadIdx.x) >> 5;
    const int sl = threadIdx.x & 31;
    if (node >= N_NODES) return;
    const int p0 = ptr[node], p1 = ptr[node + 1];
    const int sub = sl >> 4;           // edge parity within a pair
    const size_t coff = (size_t)(sl & 15) * 4;     // cols coff..coff+3
    float c0 = 0.f, c1 = 0.f, c2 = 0.f, c3 = 0.f;
    float d0 = 0.f, d1 = 0.f, d2 = 0.f, d3 = 0.f;
    int p = p0;
    for (; p + 15 < p1; p += 16) {     // 8 loads, 16 edges
        int s[8];
#pragma unroll
        for (int k = 0; k < 8; ++k) s[k] = adj[p + 2 * k + sub];
#pragma unroll
        for (int k = 0; k < 8; ++k) {
            uint2 u = *(const uint2*)(feat + (size_t)s[k] * 64 + coff);
            if (k & 1) { d0 += BFLO(u.x); d1 += BFHI(u.x); d2 += BFLO(u.y); d3 += BFHI(u.y); }
            else       { c0 += BFLO(u.x); c1 += BFHI(u.x); c2 += BFLO(u.y); c3 += BFHI(u.y); }
        }
    }
    for (; p + 7 < p1; p += 8) {       // 4 loads, 8 edges
        int s[4];
#pragma unroll
        for (int k = 0; k < 4; ++k) s[k] = adj[p + 2 * k + sub];
#pragma unroll
        for (int k = 0; k < 4; ++k) {
            uint2 u = *(const uint2*)(feat + (size_t)s[k] * 64 + coff);
            if (k & 1) { d0 += BFLO(u.x); d1 += BFHI(u.x); d2 += BFLO(u.y); d3 += BFHI(u.y); }
            else       { c0 += BFLO(u.x); c1 += BFHI(u.x); c2 += BFLO(u.y); c3 += BFHI(u.y); }
        }
    }
    for (; p + 1 < p1; p += 2) {       // 1 load, 2 edges
        int s = adj[p + sub];
        uint2 u = *(const uint2*)(feat + (size_t)s * 64 + coff);
        c0 += BFLO(u.x); c1 += BFHI(u.x); c2 += BFLO(u.y); c3 += BFHI(u.y);
    }
    if (p < p1 && sub == 0) {          // odd tail
        int s = adj[p];
        uint2 u = *(const uint2*)(feat + (size_t)s * 64 + coff);
        c0 += BFLO(u.x); c1 += BFHI(u.x); c2 += BFLO(u.y); c3 += BFHI(u.y);
    }
    c0 += d0; c1 += d1; c2 += d2; c3 += d3;
    c0 += __shfl_xor(c0, 16);
    c1 += __shfl_xor(c1, 16);
    c2 += __shfl_xor(c2, 16);
    c3 += __shfl_xor(c3, 16);
    if (sub == 0) {
        const float inv = 1.0f / (float)max(p1 - p0, 1);
        float4 z = *(const float4*)(out + (size_t)node * 64 + coff);
        z.x += c0 * inv;
        z.y += c1 * inv;
        z.z += c2 * inv;
        z.w += c3 * inv;
        *(float4*)(out + (size_t)node * 64 + coff) = z;
    }
}

// ---------------------------------------------------------------------------
extern "C" void kernel_launch(void* const* d_in, const int* in_sizes, int n_in,
                              void* d_out, int out_size, void* d_ws, size_t ws_size,
                              hipStream_t stream) {
    const float* x   = (const float*)d_in[0];
    const int*   ei  = (const int*)d_in[1];
    const float* W1l = (const float*)d_in[2];
    const float* b1  = (const float*)d_in[3];
    const float* W1r = (const float*)d_in[4];
    const float* W2l = (const float*)d_in[5];
    const float* b2  = (const float*)d_in[6];
    const float* W2r = (const float*)d_in[7];
    float* out = (float*)d_out;

    char* w = (char*)d_ws;
    int* flag   = (int*)w;                       // 64 ints
    int* bincur = flag + 64;                     // 1024 (NBIN used; counts after scatter)
    int* ptr    = bincur + 1024;                 // N+1
    int* adj    = ptr + (N_NODES + 1);           // NE
    size_t koff = (((size_t)(64 + 1024 + N_NODES + 1 + NE)) * 4 + 255)
                  & ~(size_t)255;
    unsigned long long* kmask = (unsigned long long*)(w + koff);  // 200000 ull
    size_t foff = (koff + (size_t)NMASKW * 8 + 255) & ~(size_t)255;
    __hip_bfloat16* wb    = (__hip_bfloat16*)(w + foff);        // 49152
    __hip_bfloat16* w1lb  = wb;
    __hip_bfloat16* w1rb  = wb + 16384;
    __hip_bfloat16* w2lb  = wb + 32768;
    __hip_bfloat16* w2rb  = wb + 40960;
    __hip_bfloat16* xb    = wb + 49152;                         // N*128
    __hip_bfloat16* meanb = xb + (size_t)N_NODES * 128;         // N*128
    char* pregion = (char*)(meanb + (size_t)N_NODES * 128);
    int* pairs = (int*)pregion;                      // 782*3072*4B = 9.6 MB
    __hip_bfloat16* y2b = (__hip_bfloat16*)pregion;  // [N,64] overlay (12.8 MB)

    const int n4 = N_NODES * 128 / 4;
    k_conv<<<(n4 + 255) / 256, 256, 0, stream>>>((const float4*)x, (ushort4*)xb, n4);
    k_wconv<<<192, 256, 0, stream>>>(W1l, W1r, W2l, W2r, wb);
    k_detect<<<1, 256, 0, stream>>>(ei, flag, bincur);
    k_mask<<<1024, 256, 0, stream>>>(kmask);

    k_binscatter<<<NBLK, 1024, 0, stream>>>(ei, flag, bincur, pairs);
    k_bin2csr<<<NBIN, 256, 0, stream>>>(pairs, bincur, ptr, adj);

    const int ab  = (N_NODES + 3) / 4;           // k_agg:   4 nodes / 256-block
    const int nb  = (N_NODES + 63) / 64;
    const int ab2 = (N_NODES + 7) / 8;           // k_agg2f: 8 nodes / 256-block

    k_agg<<<ab, 256, 0, stream>>>(xb, ptr, adj, meanb);
    k_lin1f<<<nb, 256, 0, stream>>>(meanb, xb, w1lb, w1rb, b1,
                                    w2lb, w2rb, b2, kmask, y2b, out);
    k_agg2f<<<ab2, 256, 0, stream>>>(y2b, ptr, adj, out);
}

// Round 9
// 243.169 us; speedup vs baseline: 3.1040x; 1.0002x over previous
//
#include <hip/hip_runtime.h>
#include <hip/hip_bf16.h>

#define N_NODES 100000
#define NE      1600000

#define BINSH 7
#define NBIN  782                      // ceil(100000 / 128)
#define BCAP  3072                     // max edges/bin (avg 2046, sigma~45)
#define SEPB  16384                    // edges per binning block
#define NBLK  ((NE + SEPB - 1) / SEPB) // 98
#define NMASKW 200000                  // 12.8M dropout bits / 64

typedef __attribute__((ext_vector_type(8))) short bfrag;   // 8 bf16 (4 VGPR)
typedef __attribute__((ext_vector_type(4))) float ffrag;   // 4 fp32 acc

#define BFLO(u) __uint_as_float((u) << 16)
#define BFHI(u) __uint_as_float((u) & 0xffff0000u)

// ---------------------------------------------------------------------------
// JAX threefry2x32, partitionable path. key=(0,42), counter=(0,f),
// bits = out0 ^ out1, keep <=> top bit == 0.
// ---------------------------------------------------------------------------
__device__ __forceinline__ unsigned tf_rotl(unsigned x, int d) {
    return (x << d) | (x >> (32 - d));
}

__device__ __forceinline__ unsigned tf_word(unsigned f) {
    const unsigned ks0 = 0u;
    const unsigned ks1 = 42u;
    const unsigned ks2 = 0x1BD11BDAu ^ 0u ^ 42u;
    unsigned x0 = 0u + ks0;
    unsigned x1 = f + ks1;
#define TF_RND(r) { x0 += x1; x1 = tf_rotl(x1, r); x1 ^= x0; }
    TF_RND(13) TF_RND(15) TF_RND(26) TF_RND(6)
    x0 += ks1; x1 += ks2 + 1u;
    TF_RND(17) TF_RND(29) TF_RND(16) TF_RND(24)
    x0 += ks2; x1 += ks0 + 2u;
    TF_RND(13) TF_RND(15) TF_RND(26) TF_RND(6)
    x0 += ks0; x1 += ks1 + 3u;
    TF_RND(17) TF_RND(29) TF_RND(16) TF_RND(24)
    x0 += ks1; x1 += ks2 + 4u;
    TF_RND(13) TF_RND(15) TF_RND(26) TF_RND(6)
    x0 += ks2; x1 += ks0 + 5u;
#undef TF_RND
    return x0 ^ x1;
}

__device__ __forceinline__ unsigned short bf_bits(float v) {
    __hip_bfloat16 b = __float2bfloat16(v);
    return *(unsigned short*)&b;
}

// ---------------------------------------------------------------------------
// Fused preprocessing: x->bf16, W->bf16, dtype probe + bincur zero, dropout
// mask. Independent sections share one launch so VALU (mask) overlaps
// memory (conv).
// ---------------------------------------------------------------------------
__global__ __launch_bounds__(256) void k_pre(
    const float4* __restrict__ x4, ushort4* __restrict__ xb4,
    const float* __restrict__ W1l, const float* __restrict__ W1r,
    const float* __restrict__ W2l, const float* __restrict__ W2r,
    __hip_bfloat16* __restrict__ wb,
    const int* __restrict__ ei, int* __restrict__ flag,
    int* __restrict__ bincur, unsigned long long* __restrict__ km) {
    const int tid0 = blockIdx.x * 256 + threadIdx.x;
    const int stride = gridDim.x * 256;

    // x fp32 -> bf16 (3.2M float4)
    for (int i = tid0; i < N_NODES * 128 / 4; i += stride) {
        float4 v = x4[i];
        ushort4 o;
        o.x = bf_bits(v.x); o.y = bf_bits(v.y);
        o.z = bf_bits(v.z); o.w = bf_bits(v.w);
        xb4[i] = o;
    }
    // W -> bf16 (49152)
    for (int i = tid0; i < 49152; i += stride) {
        float v;
        if (i < 16384)      v = W1l[i];
        else if (i < 32768) v = W1r[i - 16384];
        else if (i < 40960) v = W2l[i - 32768];
        else                v = W2r[i - 40960];
        wb[i] = __float2bfloat16(v);
    }
    // dtype probe + bincur zero (block 0 only)
    if (blockIdx.x == 0) {
        __shared__ int nz;
        if (threadIdx.x == 0) nz = 0;
        __syncthreads();
        for (int i = threadIdx.x; i < 1024; i += 256) {
            if (ei[2 * i + 1] != 0) atomicAdd(&nz, 1);
            bincur[i] = 0;
        }
        __syncthreads();
        if (threadIdx.x == 0) *flag = (nz == 0) ? 1 : 0;
    }
    // dropout keep-mask: one wave per 64-bit word
    const int lane = threadIdx.x & 63;
    const int gw = tid0 >> 6;
    const int nw = stride >> 6;
    for (int widx = gw; widx < NMASKW; widx += nw) {
        unsigned wv = tf_word((unsigned)widx * 64u + (unsigned)lane);
        unsigned long long keep = __ballot(!(wv & 0x80000000u));
        if (lane == 0) km[widx] = keep;
    }
}

// ---------------------------------------------------------------------------
// Binned CSR build. pairs packed: (dstlocal 7b << 17) | src 17b.
// ---------------------------------------------------------------------------
__global__ __launch_bounds__(1024) void k_binscatter(const int* __restrict__ ei,
        const int* __restrict__ flag, int* __restrict__ bincur,
        int* __restrict__ pairs) {
    __shared__ int h[NBIN];
    __shared__ int lbase[NBIN];
    for (int i = threadIdx.x; i < NBIN; i += 1024) h[i] = 0;
    __syncthreads();
    const int is64 = *flag;
    const int e0 = blockIdx.x * SEPB + threadIdx.x;
    int d[16], s[16];
#pragma unroll
    for (int k = 0; k < 16; ++k) {
        int e = e0 + k * 1024;
        if (e < NE) {
            d[k] = is64 ? ei[2 * (NE + e)] : ei[NE + e];
            s[k] = is64 ? ei[2 * e]        : ei[e];
            atomicAdd(&h[d[k] >> BINSH], 1);
        } else {
            d[k] = -1; s[k] = 0;
        }
    }
    __syncthreads();
    for (int i = threadIdx.x; i < NBIN; i += 1024) {
        int c = h[i];
        lbase[i] = c ? atomicAdd(&bincur[i], c) : 0;
        h[i] = 0;                      // reuse as intra-block rank counter
    }
    __syncthreads();
#pragma unroll
    for (int k = 0; k < 16; ++k) {
        if (d[k] >= 0) {
            int b = d[k] >> BINSH;
            int r = atomicAdd(&h[b], 1);
            pairs[(size_t)b * BCAP + lbase[b] + r] =
                ((d[k] & 127) << 17) | s[k];
        }
    }
}

__global__ __launch_bounds__(256) void k_bin2csr(const int* __restrict__ pairs,
        const int* __restrict__ bincnt, int* __restrict__ ptr,
        int* __restrict__ adj) {
    __shared__ int red[256];
    __shared__ int cnt[128];
    __shared__ int sc[128];
    __shared__ int woff[128];
    const int b = blockIdx.x;
    const int t = threadIdx.x;
    int s = 0;
    for (int i = t; i < b; i += 256) s += bincnt[i];
    red[t] = s;
    __syncthreads();
    for (int o = 128; o > 0; o >>= 1) {
        if (t < o) red[t] += red[t + o];
        __syncthreads();
    }
    const int base = red[0];
    const int nb = bincnt[b];
    const int* pb = pairs + (size_t)b * BCAP;
    if (t < 128) cnt[t] = 0;
    __syncthreads();
    for (int i = t; i < nb; i += 256)
        atomicAdd(&cnt[(pb[i] >> 17) & 127], 1);
    __syncthreads();
    if (t < 128) sc[t] = cnt[t];
    __syncthreads();
    for (int o = 1; o < 128; o <<= 1) {
        int u = 0;
        if (t < 128 && t >= o) u = sc[t - o];
        __syncthreads();
        if (t < 128) sc[t] += u;
        __syncthreads();
    }
    if (t < 128) {
        int ex = sc[t] - cnt[t];
        int node = b * 128 + t;
        if (node <= N_NODES) ptr[node] = base + ex;
        woff[t] = ex;
    }
    __syncthreads();
    for (int i = t; i < nb; i += 256) {
        int pk = pb[i];
        int r = atomicAdd(&woff[(pk >> 17) & 127], 1);
        adj[base + r] = pk & 0x1FFFF;
    }
}

// ---------------------------------------------------------------------------
// bf16 pull aggregation, 128-dim: one wave per node, 2 edges per load issue
// (half-wave x 8B), up to 16 edges in flight; shfl_xor(32) combine.
// (Service-floor bound: ~205MB compulsory L2-fill @ ~3TB/s — r8 A/B null.)
// ---------------------------------------------------------------------------
__global__ void k_agg(const __hip_bfloat16* __restrict__ feat,
                      const int* __restrict__ ptr, const int* __restrict__ adj,
                      __hip_bfloat16* __restrict__ mean) {
    const int wid = (blockIdx.x * blockDim.x + threadIdx.x) >> 6;
    const int lane = threadIdx.x & 63;
    if (wid >= N_NODES) return;
    const int p0 = ptr[wid], p1 = ptr[wid + 1];
    const int half = lane >> 5;
    const size_t coff = (size_t)(lane & 31) * 4;
    float c0 = 0.f, c1 = 0.f, c2 = 0.f, c3 = 0.f;
    float d0 = 0.f, d1 = 0.f, d2 = 0.f, d3 = 0.f;
    int p = p0;
    for (; p + 15 < p1; p += 16) {
        int s[8];
#pragma unroll
        for (int k = 0; k < 8; ++k) s[k] = adj[p + 2 * k + half];
#pragma unroll
        for (int k = 0; k < 8; ++k) {
            uint2 u = *(const uint2*)(feat + (size_t)s[k] * 128 + coff);
            if (k & 1) { d0 += BFLO(u.x); d1 += BFHI(u.x); d2 += BFLO(u.y); d3 += BFHI(u.y); }
            else       { c0 += BFLO(u.x); c1 += BFHI(u.x); c2 += BFLO(u.y); c3 += BFHI(u.y); }
        }
    }
    for (; p + 7 < p1; p += 8) {
        int s[4];
#pragma unroll
        for (int k = 0; k < 4; ++k) s[k] = adj[p + 2 * k + half];
#pragma unroll
        for (int k = 0; k < 4; ++k) {
            uint2 u = *(const uint2*)(feat + (size_t)s[k] * 128 + coff);
            if (k & 1) { d0 += BFLO(u.x); d1 += BFHI(u.x); d2 += BFLO(u.y); d3 += BFHI(u.y); }
            else       { c0 += BFLO(u.x); c1 += BFHI(u.x); c2 += BFLO(u.y); c3 += BFHI(u.y); }
        }
    }
    for (; p + 1 < p1; p += 2) {
        int s = adj[p + half];
        uint2 u = *(const uint2*)(feat + (size_t)s * 128 + coff);
        c0 += BFLO(u.x); c1 += BFHI(u.x); c2 += BFLO(u.y); c3 += BFHI(u.y);
    }
    if (p < p1 && half == 0) {
        int s = adj[p];
        uint2 u = *(const uint2*)(feat + (size_t)s * 128 + coff);
        c0 += BFLO(u.x); c1 += BFHI(u.x); c2 += BFLO(u.y); c3 += BFHI(u.y);
    }
    c0 += d0; c1 += d1; c2 += d2; c3 += d3;
    c0 += __shfl_xor(c0, 32);
    c1 += __shfl_xor(c1, 32);
    c2 += __shfl_xor(c2, 32);
    c3 += __shfl_xor(c3, 32);
    if (half == 0) {
        const float inv = 1.0f / (float)max(p1 - p0, 1);
        uint2 o;
        o.x = ((unsigned)bf_bits(c1 * inv) << 16) | (unsigned)bf_bits(c0 * inv);
        o.y = ((unsigned)bf_bits(c3 * inv) << 16) | (unsigned)bf_bits(c2 * inv);
        *(uint2*)(mean + (size_t)wid * 128 + coff) = o;
    }
}

// ---------------------------------------------------------------------------
// Fused layer1 + layer2-projections, 32-row tiles (3125 blocks: 2x residency
// vs 64-row; 100000%32==0 so no bounds clamps) + register double-buffer on
// the A-fragment loads (prefetch t+1 under t's MFMA+epilogue).
//   h = dropout(relu(mean·W1l^T + x·W1r^T + b1))   (LDS only)
//   y2 = h·W2l^T (bf16)   z = h·W2r^T + b2 -> d_out
// MFMA 16x16x32 bf16; C/D: col=lane&15, row=(lane>>4)*4+reg  [m89].
// ---------------------------------------------------------------------------
__global__ __launch_bounds__(256) void k_lin1f(
    const __hip_bfloat16* __restrict__ Am, const __hip_bfloat16* __restrict__ Ax,
    const __hip_bfloat16* __restrict__ W1l, const __hip_bfloat16* __restrict__ W1r,
    const float* __restrict__ b1,
    const __hip_bfloat16* __restrict__ W2l, const __hip_bfloat16* __restrict__ W2r,
    const float* __restrict__ b2,
    const unsigned long long* __restrict__ kmask,
    __hip_bfloat16* __restrict__ y2, float* __restrict__ zout) {
    __shared__ __align__(16) __hip_bfloat16 hs[32][136];
    const int tid = threadIdx.x;
    const int w  = tid >> 6;
    const int l  = tid & 63;
    const int lr = l & 15;
    const int lk = l >> 4;
    const int j0 = w * 32;           // phase-1 h-cols owned by this wave
    const int j2 = w * 16 + lr;      // phase-2 out-col
    const int n0 = blockIdx.x * 32;

    bfrag B1[2][2][4];
#pragma unroll
    for (int jt = 0; jt < 2; ++jt) {
        const int jrow = j0 + jt * 16 + lr;
#pragma unroll
        for (int ks = 0; ks < 4; ++ks) {
            B1[jt][0][ks] = *(const bfrag*)(W1l + jrow * 128 + ks * 32 + lk * 8);
            B1[jt][1][ks] = *(const bfrag*)(W1r + jrow * 128 + ks * 32 + lk * 8);
        }
    }
    bfrag Bl2[4], Br2[4];
#pragma unroll
    for (int ks = 0; ks < 4; ++ks) {
        Bl2[ks] = *(const bfrag*)(W2l + j2 * 128 + ks * 32 + lk * 8);
        Br2[ks] = *(const bfrag*)(W2r + j2 * 128 + ks * 32 + lk * 8);
    }
    const float bj0 = b1[j0 + lr];
    const float bj1 = b1[j0 + 16 + lr];
    const float bj2 = b2[j2];

    // ---- phase 1: h tile -> LDS, A-loads double-buffered ------------------
    bfrag amc[4], axc[4], amn[4], axn[4];
    {
        const size_t arow = (size_t)(n0 + lr);
#pragma unroll
        for (int ks = 0; ks < 4; ++ks) {
            amc[ks] = *(const bfrag*)(Am + arow * 128 + ks * 32 + lk * 8);
            axc[ks] = *(const bfrag*)(Ax + arow * 128 + ks * 32 + lk * 8);
        }
    }
#pragma unroll
    for (int t = 0; t < 2; ++t) {
        if (t < 1) {
            const size_t arow = (size_t)(n0 + 16 + lr);
#pragma unroll
            for (int ks = 0; ks < 4; ++ks) {
                amn[ks] = *(const bfrag*)(Am + arow * 128 + ks * 32 + lk * 8);
                axn[ks] = *(const bfrag*)(Ax + arow * 128 + ks * 32 + lk * 8);
            }
        }
        ffrag acc0 = {0.f, 0.f, 0.f, 0.f};
        ffrag acc1 = {0.f, 0.f, 0.f, 0.f};
#pragma unroll
        for (int ks = 0; ks < 4; ++ks) {
            acc0 = __builtin_amdgcn_mfma_f32_16x16x32_bf16(amc[ks], B1[0][0][ks], acc0, 0, 0, 0);
            acc1 = __builtin_amdgcn_mfma_f32_16x16x32_bf16(amc[ks], B1[1][0][ks], acc1, 0, 0, 0);
            acc0 = __builtin_amdgcn_mfma_f32_16x16x32_bf16(axc[ks], B1[0][1][ks], acc0, 0, 0, 0);
            acc1 = __builtin_amdgcn_mfma_f32_16x16x32_bf16(axc[ks], B1[1][1][ks], acc1, 0, 0, 0);
        }
#pragma unroll
        for (int r = 0; r < 4; ++r) {
            const int n = n0 + t * 16 + lk * 4 + r;
            const int lrow = t * 16 + lk * 4 + r;
            const unsigned long long km = kmask[n * 2 + (j0 >> 6)];
            float v0 = fmaxf(acc0[r] + bj0, 0.f);
            v0 = ((km >> ((j0 + lr) & 63)) & 1ull) ? (v0 + v0) : 0.f;
            hs[lrow][j0 + lr] = __float2bfloat16(v0);
            float v1 = fmaxf(acc1[r] + bj1, 0.f);
            v1 = ((km >> ((j0 + 16 + lr) & 63)) & 1ull) ? (v1 + v1) : 0.f;
            hs[lrow][j0 + 16 + lr] = __float2bfloat16(v1);
        }
#pragma unroll
        for (int ks = 0; ks < 4; ++ks) { amc[ks] = amn[ks]; axc[ks] = axn[ks]; }
    }
    __syncthreads();

    // ---- phase 2: y2 = h·W2l^T, z = h·W2r^T + b2 --------------------------
#pragma unroll
    for (int t = 0; t < 2; ++t) {
        ffrag accY = {0.f, 0.f, 0.f, 0.f};
        ffrag accZ = {0.f, 0.f, 0.f, 0.f};
#pragma unroll
        for (int ks = 0; ks < 4; ++ks) {
            bfrag ah = *(const bfrag*)&hs[t * 16 + lr][ks * 32 + lk * 8];
            accY = __builtin_amdgcn_mfma_f32_16x16x32_bf16(ah, Bl2[ks], accY, 0, 0, 0);
            accZ = __builtin_amdgcn_mfma_f32_16x16x32_bf16(ah, Br2[ks], accZ, 0, 0, 0);
        }
#pragma unroll
        for (int r = 0; r < 4; ++r) {
            const int n = n0 + t * 16 + lk * 4 + r;
            y2[(size_t)n * 64 + j2]   = __float2bfloat16(accY[r]);
            zout[(size_t)n * 64 + j2] = accZ[r] + bj2;
        }
    }
}

// ---------------------------------------------------------------------------
// Layer-2 gather+finish: out[n][:] = z[n][:] + mean_{nbr} y2[nbr][:]
// 64-dim rows, 2 nodes/wave; 2 edges per load issue; shfl_xor(16) combine.
// ---------------------------------------------------------------------------
__global__ void k_agg2f(const __hip_bfloat16* __restrict__ feat,
                        const int* __restrict__ ptr, const int* __restrict__ adj,
                        float* __restrict__ out) {
    const int node = (blockIdx.x * blockDim.x + threadIdx.x) >> 5;
    const int sl = threadIdx.x & 31;
    if (node >= N_NODES) return;
    const int p0 = ptr[node], p1 = ptr[node + 1];
    const int sub = sl >> 4;
    const size_t coff = (size_t)(sl & 15) * 4;
    float c0 = 0.f, c1 = 0.f, c2 = 0.f, c3 = 0.f;
    float d0 = 0.f, d1 = 0.f, d2 = 0.f, d3 = 0.f;
    int p = p0;
    for (; p + 15 < p1; p += 16) {
        int s[8];
#pragma unroll
        for (int k = 0; k < 8; ++k) s[k] = adj[p + 2 * k + sub];
#pragma unroll
        for (int k = 0; k < 8; ++k) {
            uint2 u = *(const uint2*)(feat + (size_t)s[k] * 64 + coff);
            if (k & 1) { d0 += BFLO(u.x); d1 += BFHI(u.x); d2 += BFLO(u.y); d3 += BFHI(u.y); }
            else       { c0 += BFLO(u.x); c1 += BFHI(u.x); c2 += BFLO(u.y); c3 += BFHI(u.y); }
        }
    }
    for (; p + 7 < p1; p += 8) {
        int s[4];
#pragma unroll
        for (int k = 0; k < 4; ++k) s[k] = adj[p + 2 * k + sub];
#pragma unroll
        for (int k = 0; k < 4; ++k) {
            uint2 u = *(const uint2*)(feat + (size_t)s[k] * 64 + coff);
            if (k & 1) { d0 += BFLO(u.x); d1 += BFHI(u.x); d2 += BFLO(u.y); d3 += BFHI(u.y); }
            else       { c0 += BFLO(u.x); c1 += BFHI(u.x); c2 += BFLO(u.y); c3 += BFHI(u.y); }
        }
    }
    for (; p + 1 < p1; p += 2) {
        int s = adj[p + sub];
        uint2 u = *(const uint2*)(feat + (size_t)s * 64 + coff);
        c0 += BFLO(u.x); c1 += BFHI(u.x); c2 += BFLO(u.y); c3 += BFHI(u.y);
    }
    if (p < p1 && sub == 0) {
        int s = adj[p];
        uint2 u = *(const uint2*)(feat + (size_t)s * 64 + coff);
        c0 += BFLO(u.x); c1 += BFHI(u.x); c2 += BFLO(u.y); c3 += BFHI(u.y);
    }
    c0 += d0; c1 += d1; c2 += d2; c3 += d3;
    c0 += __shfl_xor(c0, 16);
    c1 += __shfl_xor(c1, 16);
    c2 += __shfl_xor(c2, 16);
    c3 += __shfl_xor(c3, 16);
    if (sub == 0) {
        const float inv = 1.0f / (float)max(p1 - p0, 1);
        float4 z = *(const float4*)(out + (size_t)node * 64 + coff);
        z.x += c0 * inv;
        z.y += c1 * inv;
        z.z += c2 * inv;
        z.w += c3 * inv;
        *(float4*)(out + (size_t)node * 64 + coff) = z;
    }
}

// ---------------------------------------------------------------------------
extern "C" void kernel_launch(void* const* d_in, const int* in_sizes, int n_in,
                              void* d_out, int out_size, void* d_ws, size_t ws_size,
                              hipStream_t stream) {
    const float* x   = (const float*)d_in[0];
    const int*   ei  = (const int*)d_in[1];
    const float* W1l = (const float*)d_in[2];
    const float* b1  = (const float*)d_in[3];
    const float* W1r = (const float*)d_in[4];
    const float* W2l = (const float*)d_in[5];
    const float* b2  = (const float*)d_in[6];
    const float* W2r = (const float*)d_in[7];
    float* out = (float*)d_out;

    char* w = (char*)d_ws;
    int* flag   = (int*)w;                       // 64 ints
    int* bincur = flag + 64;                     // 1024 (NBIN used)
    int* ptr    = bincur + 1024;                 // N+1
    int* adj    = ptr + (N_NODES + 1);           // NE
    size_t koff = (((size_t)(64 + 1024 + N_NODES + 1 + NE)) * 4 + 255)
                  & ~(size_t)255;
    unsigned long long* kmask = (unsigned long long*)(w + koff);  // 200000 ull
    size_t foff = (koff + (size_t)NMASKW * 8 + 255) & ~(size_t)255;
    __hip_bfloat16* wb    = (__hip_bfloat16*)(w + foff);        // 49152
    __hip_bfloat16* w1lb  = wb;
    __hip_bfloat16* w1rb  = wb + 16384;
    __hip_bfloat16* w2lb  = wb + 32768;
    __hip_bfloat16* w2rb  = wb + 40960;
    __hip_bfloat16* xb    = wb + 49152;                         // N*128
    __hip_bfloat16* meanb = xb + (size_t)N_NODES * 128;         // N*128
    char* pregion = (char*)(meanb + (size_t)N_NODES * 128);
    int* pairs = (int*)pregion;                      // 782*3072*4B = 9.6 MB
    __hip_bfloat16* y2b = (__hip_bfloat16*)pregion;  // [N,64] overlay (12.8 MB)

    k_pre<<<2048, 256, 0, stream>>>((const float4*)x, (ushort4*)xb,
                                    W1l, W1r, W2l, W2r, wb,
                                    ei, flag, bincur, kmask);

    k_binscatter<<<NBLK, 1024, 0, stream>>>(ei, flag, bincur, pairs);
    k_bin2csr<<<NBIN, 256, 0, stream>>>(pairs, bincur, ptr, adj);

    const int ab  = (N_NODES + 3) / 4;           // k_agg:   4 nodes / 256-block
    const int nb1 = N_NODES / 32;                // k_lin1f: 3125 blocks
    const int ab2 = (N_NODES + 7) / 8;           // k_agg2f: 8 nodes / 256-block

    k_agg<<<ab, 256, 0, stream>>>(xb, ptr, adj, meanb);
    k_lin1f<<<nb1, 256, 0, stream>>>(meanb, xb, w1lb, w1rb, b1,
                                     w2lb, w2rb, b2, kmask, y2b, out);
    k_agg2f<<<ab2, 256, 0, stream>>>(y2b, ptr, adj, out);
}

// Round 10
// 233.217 us; speedup vs baseline: 3.2364x; 1.0427x over previous
//
#include <hip/hip_runtime.h>
#include <hip/hip_bf16.h>

#define N_NODES 100000
#define NE      1600000

#define BINSH 7
#define NBIN  782                      // ceil(100000 / 128)
#define BCAP  3072                     // max edges/bin (avg 2046, sigma~45)
#define SEPB  16384                    // edges per binning block
#define NBLK  ((NE + SEPB - 1) / SEPB) // 98
#define NMASKW 200000                  // 12.8M dropout bits / 64

typedef __attribute__((ext_vector_type(8))) short bfrag;   // 8 bf16 (4 VGPR)
typedef __attribute__((ext_vector_type(4))) float ffrag;   // 4 fp32 acc

#define BFLO(u) __uint_as_float((u) << 16)
#define BFHI(u) __uint_as_float((u) & 0xffff0000u)

// ---------------------------------------------------------------------------
// JAX threefry2x32, partitionable path. key=(0,42), counter=(0,f),
// bits = out0 ^ out1, keep <=> top bit == 0.
// ---------------------------------------------------------------------------
__device__ __forceinline__ unsigned tf_rotl(unsigned x, int d) {
    return (x << d) | (x >> (32 - d));
}

__device__ __forceinline__ unsigned tf_word(unsigned f) {
    const unsigned ks0 = 0u;
    const unsigned ks1 = 42u;
    const unsigned ks2 = 0x1BD11BDAu ^ 0u ^ 42u;
    unsigned x0 = 0u + ks0;
    unsigned x1 = f + ks1;
#define TF_RND(r) { x0 += x1; x1 = tf_rotl(x1, r); x1 ^= x0; }
    TF_RND(13) TF_RND(15) TF_RND(26) TF_RND(6)
    x0 += ks1; x1 += ks2 + 1u;
    TF_RND(17) TF_RND(29) TF_RND(16) TF_RND(24)
    x0 += ks2; x1 += ks0 + 2u;
    TF_RND(13) TF_RND(15) TF_RND(26) TF_RND(6)
    x0 += ks0; x1 += ks1 + 3u;
    TF_RND(17) TF_RND(29) TF_RND(16) TF_RND(24)
    x0 += ks1; x1 += ks2 + 4u;
    TF_RND(13) TF_RND(15) TF_RND(26) TF_RND(6)
    x0 += ks2; x1 += ks0 + 5u;
#undef TF_RND
    return x0 ^ x1;
}

__device__ __forceinline__ unsigned short bf_bits(float v) {
    __hip_bfloat16 b = __float2bfloat16(v);
    return *(unsigned short*)&b;
}

// ---------------------------------------------------------------------------
// Fused preprocessing: x->bf16, W->bf16, dtype probe + bincur zero, dropout
// mask (VALU overlaps conv's memory traffic).
// ---------------------------------------------------------------------------
__global__ __launch_bounds__(256) void k_pre(
    const float4* __restrict__ x4, ushort4* __restrict__ xb4,
    const float* __restrict__ W1l, const float* __restrict__ W1r,
    const float* __restrict__ W2l, const float* __restrict__ W2r,
    __hip_bfloat16* __restrict__ wb,
    const int* __restrict__ ei, int* __restrict__ flag,
    int* __restrict__ bincur, unsigned long long* __restrict__ km) {
    const int tid0 = blockIdx.x * 256 + threadIdx.x;
    const int stride = gridDim.x * 256;

    for (int i = tid0; i < N_NODES * 128 / 4; i += stride) {
        float4 v = x4[i];
        ushort4 o;
        o.x = bf_bits(v.x); o.y = bf_bits(v.y);
        o.z = bf_bits(v.z); o.w = bf_bits(v.w);
        xb4[i] = o;
    }
    for (int i = tid0; i < 49152; i += stride) {
        float v;
        if (i < 16384)      v = W1l[i];
        else if (i < 32768) v = W1r[i - 16384];
        else if (i < 40960) v = W2l[i - 32768];
        else                v = W2r[i - 40960];
        wb[i] = __float2bfloat16(v);
    }
    if (blockIdx.x == 0) {
        __shared__ int nz;
        if (threadIdx.x == 0) nz = 0;
        __syncthreads();
        for (int i = threadIdx.x; i < 1024; i += 256) {
            if (ei[2 * i + 1] != 0) atomicAdd(&nz, 1);
            bincur[i] = 0;
        }
        __syncthreads();
        if (threadIdx.x == 0) *flag = (nz == 0) ? 1 : 0;
    }
    const int lane = threadIdx.x & 63;
    const int gw = tid0 >> 6;
    const int nw = stride >> 6;
    for (int widx = gw; widx < NMASKW; widx += nw) {
        unsigned wv = tf_word((unsigned)widx * 64u + (unsigned)lane);
        unsigned long long keep = __ballot(!(wv & 0x80000000u));
        if (lane == 0) km[widx] = keep;
    }
}

// ---------------------------------------------------------------------------
// Binned CSR build. pairs packed: (dstlocal 7b << 17) | src 17b.
// ---------------------------------------------------------------------------
__global__ __launch_bounds__(1024) void k_binscatter(const int* __restrict__ ei,
        const int* __restrict__ flag, int* __restrict__ bincur,
        int* __restrict__ pairs) {
    __shared__ int h[NBIN];
    __shared__ int lbase[NBIN];
    for (int i = threadIdx.x; i < NBIN; i += 1024) h[i] = 0;
    __syncthreads();
    const int is64 = *flag;
    const int e0 = blockIdx.x * SEPB + threadIdx.x;
    int d[16], s[16];
#pragma unroll
    for (int k = 0; k < 16; ++k) {
        int e = e0 + k * 1024;
        if (e < NE) {
            d[k] = is64 ? ei[2 * (NE + e)] : ei[NE + e];
            s[k] = is64 ? ei[2 * e]        : ei[e];
            atomicAdd(&h[d[k] >> BINSH], 1);
        } else {
            d[k] = -1; s[k] = 0;
        }
    }
    __syncthreads();
    for (int i = threadIdx.x; i < NBIN; i += 1024) {
        int c = h[i];
        lbase[i] = c ? atomicAdd(&bincur[i], c) : 0;
        h[i] = 0;                      // reuse as intra-block rank counter
    }
    __syncthreads();
#pragma unroll
    for (int k = 0; k < 16; ++k) {
        if (d[k] >= 0) {
            int b = d[k] >> BINSH;
            int r = atomicAdd(&h[b], 1);
            pairs[(size_t)b * BCAP + lbase[b] + r] =
                ((d[k] & 127) << 17) | s[k];
        }
    }
}

__global__ __launch_bounds__(256) void k_bin2csr(const int* __restrict__ pairs,
        const int* __restrict__ bincnt, int* __restrict__ ptr,
        int* __restrict__ adj) {
    __shared__ int red[256];
    __shared__ int cnt[128];
    __shared__ int sc[128];
    __shared__ int woff[128];
    const int b = blockIdx.x;
    const int t = threadIdx.x;
    int s = 0;
    for (int i = t; i < b; i += 256) s += bincnt[i];
    red[t] = s;
    __syncthreads();
    for (int o = 128; o > 0; o >>= 1) {
        if (t < o) red[t] += red[t + o];
        __syncthreads();
    }
    const int base = red[0];
    const int nb = bincnt[b];
    const int* pb = pairs + (size_t)b * BCAP;
    if (t < 128) cnt[t] = 0;
    __syncthreads();
    for (int i = t; i < nb; i += 256)
        atomicAdd(&cnt[(pb[i] >> 17) & 127], 1);
    __syncthreads();
    if (t < 128) sc[t] = cnt[t];
    __syncthreads();
    for (int o = 1; o < 128; o <<= 1) {
        int u = 0;
        if (t < 128 && t >= o) u = sc[t - o];
        __syncthreads();
        if (t < 128) sc[t] += u;
        __syncthreads();
    }
    if (t < 128) {
        int ex = sc[t] - cnt[t];
        int node = b * 128 + t;
        if (node <= N_NODES) ptr[node] = base + ex;
        woff[t] = ex;
    }
    __syncthreads();
    for (int i = t; i < nb; i += 256) {
        int pk = pb[i];
        int r = atomicAdd(&woff[(pk >> 17) & 127], 1);
        adj[base + r] = pk & 0x1FFFF;
    }
}

// ---------------------------------------------------------------------------
// bf16 pull aggregation, 128-dim: one wave per node, 2 edges per load issue
// (half-wave x 8B); shfl_xor(32) combine.
// (Service-floor bound: ~205MB compulsory per-XCD L2 fill @ ~3TB/s — r8 A/B null.)
// ---------------------------------------------------------------------------
__global__ void k_agg(const __hip_bfloat16* __restrict__ feat,
                      const int* __restrict__ ptr, const int* __restrict__ adj,
                      __hip_bfloat16* __restrict__ mean) {
    const int wid = (blockIdx.x * blockDim.x + threadIdx.x) >> 6;
    const int lane = threadIdx.x & 63;
    if (wid >= N_NODES) return;
    const int p0 = ptr[wid], p1 = ptr[wid + 1];
    const int half = lane >> 5;
    const size_t coff = (size_t)(lane & 31) * 4;
    float c0 = 0.f, c1 = 0.f, c2 = 0.f, c3 = 0.f;
    float d0 = 0.f, d1 = 0.f, d2 = 0.f, d3 = 0.f;
    int p = p0;
    for (; p + 15 < p1; p += 16) {
        int s[8];
#pragma unroll
        for (int k = 0; k < 8; ++k) s[k] = adj[p + 2 * k + half];
#pragma unroll
        for (int k = 0; k < 8; ++k) {
            uint2 u = *(const uint2*)(feat + (size_t)s[k] * 128 + coff);
            if (k & 1) { d0 += BFLO(u.x); d1 += BFHI(u.x); d2 += BFLO(u.y); d3 += BFHI(u.y); }
            else       { c0 += BFLO(u.x); c1 += BFHI(u.x); c2 += BFLO(u.y); c3 += BFHI(u.y); }
        }
    }
    for (; p + 7 < p1; p += 8) {
        int s[4];
#pragma unroll
        for (int k = 0; k < 4; ++k) s[k] = adj[p + 2 * k + half];
#pragma unroll
        for (int k = 0; k < 4; ++k) {
            uint2 u = *(const uint2*)(feat + (size_t)s[k] * 128 + coff);
            if (k & 1) { d0 += BFLO(u.x); d1 += BFHI(u.x); d2 += BFLO(u.y); d3 += BFHI(u.y); }
            else       { c0 += BFLO(u.x); c1 += BFHI(u.x); c2 += BFLO(u.y); c3 += BFHI(u.y); }
        }
    }
    for (; p + 1 < p1; p += 2) {
        int s = adj[p + half];
        uint2 u = *(const uint2*)(feat + (size_t)s * 128 + coff);
        c0 += BFLO(u.x); c1 += BFHI(u.x); c2 += BFLO(u.y); c3 += BFHI(u.y);
    }
    if (p < p1 && half == 0) {
        int s = adj[p];
        uint2 u = *(const uint2*)(feat + (size_t)s * 128 + coff);
        c0 += BFLO(u.x); c1 += BFHI(u.x); c2 += BFLO(u.y); c3 += BFHI(u.y);
    }
    c0 += d0; c1 += d1; c2 += d2; c3 += d3;
    c0 += __shfl_xor(c0, 32);
    c1 += __shfl_xor(c1, 32);
    c2 += __shfl_xor(c2, 32);
    c3 += __shfl_xor(c3, 32);
    if (half == 0) {
        const float inv = 1.0f / (float)max(p1 - p0, 1);
        uint2 o;
        o.x = ((unsigned)bf_bits(c1 * inv) << 16) | (unsigned)bf_bits(c0 * inv);
        o.y = ((unsigned)bf_bits(c3 * inv) << 16) | (unsigned)bf_bits(c2 * inv);
        *(uint2*)(mean + (size_t)wid * 128 + coff) = o;
    }
}

// ---------------------------------------------------------------------------
// Fused layer1 + layer2-projections (r7 64-row structure — r9's 32-row tile
// regressed 62->68us; reverted).
//   h = dropout(relu(mean·W1l^T + x·W1r^T + b1))   (LDS only)
//   y2 = h·W2l^T (bf16)   z = h·W2r^T + b2 (bf16 scratch; agg2f finishes)
// MFMA 16x16x32 bf16; C/D: col=lane&15, row=(lane>>4)*4+reg  [m89].
// ---------------------------------------------------------------------------
__global__ __launch_bounds__(256) void k_lin1f(
    const __hip_bfloat16* __restrict__ Am, const __hip_bfloat16* __restrict__ Ax,
    const __hip_bfloat16* __restrict__ W1l, const __hip_bfloat16* __restrict__ W1r,
    const float* __restrict__ b1,
    const __hip_bfloat16* __restrict__ W2l, const __hip_bfloat16* __restrict__ W2r,
    const float* __restrict__ b2,
    const unsigned long long* __restrict__ kmask,
    __hip_bfloat16* __restrict__ y2, __hip_bfloat16* __restrict__ zb) {
    __shared__ __align__(16) __hip_bfloat16 hs[64][136];   // +8 pad: bank spread
    const int tid = threadIdx.x;
    const int w  = tid >> 6;
    const int l  = tid & 63;
    const int lr = l & 15;
    const int lk = l >> 4;
    const int j0 = w * 32;           // phase-1 h-cols owned by this wave
    const int j2 = w * 16 + lr;      // phase-2 out-col
    const int n0 = blockIdx.x * 64;

    bfrag B1[2][2][4];
#pragma unroll
    for (int jt = 0; jt < 2; ++jt) {
        const int jrow = j0 + jt * 16 + lr;
#pragma unroll
        for (int ks = 0; ks < 4; ++ks) {
            B1[jt][0][ks] = *(const bfrag*)(W1l + jrow * 128 + ks * 32 + lk * 8);
            B1[jt][1][ks] = *(const bfrag*)(W1r + jrow * 128 + ks * 32 + lk * 8);
        }
    }
    bfrag Bl2[4], Br2[4];
#pragma unroll
    for (int ks = 0; ks < 4; ++ks) {
        Bl2[ks] = *(const bfrag*)(W2l + j2 * 128 + ks * 32 + lk * 8);
        Br2[ks] = *(const bfrag*)(W2r + j2 * 128 + ks * 32 + lk * 8);
    }
    const float bj0 = b1[j0 + lr];
    const float bj1 = b1[j0 + 16 + lr];
    const float bj2 = b2[j2];

    // ---- phase 1: h tile -> LDS -------------------------------------------
    for (int t = 0; t < 4; ++t) {
        const int rbase = n0 + t * 16;
        int arow = rbase + lr;
        if (arow > N_NODES - 1) arow = N_NODES - 1;
        ffrag acc0 = {0.f, 0.f, 0.f, 0.f};
        ffrag acc1 = {0.f, 0.f, 0.f, 0.f};
#pragma unroll
        for (int ks = 0; ks < 4; ++ks) {
            bfrag am = *(const bfrag*)(Am + (size_t)arow * 128 + ks * 32 + lk * 8);
            bfrag ax = *(const bfrag*)(Ax + (size_t)arow * 128 + ks * 32 + lk * 8);
            acc0 = __builtin_amdgcn_mfma_f32_16x16x32_bf16(am, B1[0][0][ks], acc0, 0, 0, 0);
            acc1 = __builtin_amdgcn_mfma_f32_16x16x32_bf16(am, B1[1][0][ks], acc1, 0, 0, 0);
            acc0 = __builtin_amdgcn_mfma_f32_16x16x32_bf16(ax, B1[0][1][ks], acc0, 0, 0, 0);
            acc1 = __builtin_amdgcn_mfma_f32_16x16x32_bf16(ax, B1[1][1][ks], acc1, 0, 0, 0);
        }
#pragma unroll
        for (int r = 0; r < 4; ++r) {
            const int n = rbase + lk * 4 + r;
            const int lrow = t * 16 + lk * 4 + r;
            const int nm = (n < N_NODES) ? n : (N_NODES - 1);
            const unsigned long long km = kmask[nm * 2 + (j0 >> 6)];
            float v0 = fmaxf(acc0[r] + bj0, 0.f);
            v0 = ((km >> ((j0 + lr) & 63)) & 1ull) ? (v0 + v0) : 0.f;
            hs[lrow][j0 + lr] = __float2bfloat16(v0);
            float v1 = fmaxf(acc1[r] + bj1, 0.f);
            v1 = ((km >> ((j0 + 16 + lr) & 63)) & 1ull) ? (v1 + v1) : 0.f;
            hs[lrow][j0 + 16 + lr] = __float2bfloat16(v1);
        }
    }
    __syncthreads();

    // ---- phase 2: y2 = h·W2l^T, z = h·W2r^T + b2 (bf16) -------------------
    for (int t = 0; t < 4; ++t) {
        ffrag accY = {0.f, 0.f, 0.f, 0.f};
        ffrag accZ = {0.f, 0.f, 0.f, 0.f};
#pragma unroll
        for (int ks = 0; ks < 4; ++ks) {
            bfrag ah = *(const bfrag*)&hs[t * 16 + lr][ks * 32 + lk * 8];
            accY = __builtin_amdgcn_mfma_f32_16x16x32_bf16(ah, Bl2[ks], accY, 0, 0, 0);
            accZ = __builtin_amdgcn_mfma_f32_16x16x32_bf16(ah, Br2[ks], accZ, 0, 0, 0);
        }
#pragma unroll
        for (int r = 0; r < 4; ++r) {
            const int n = n0 + t * 16 + lk * 4 + r;
            if (n < N_NODES) {
                y2[(size_t)n * 64 + j2] = __float2bfloat16(accY[r]);
                zb[(size_t)n * 64 + j2] = __float2bfloat16(accZ[r] + bj2);
            }
        }
    }
}

// ---------------------------------------------------------------------------
// Layer-2 gather+finish: out[n][:] = z[n][:] + mean_{nbr} y2[nbr][:]
// z read as bf16 scratch; out is a pure coalesced fp32 write (no RMW).
// ---------------------------------------------------------------------------
__global__ void k_agg2f(const __hip_bfloat16* __restrict__ feat,
                        const int* __restrict__ ptr, const int* __restrict__ adj,
                        const __hip_bfloat16* __restrict__ zb,
                        float* __restrict__ out) {
    const int node = (blockIdx.x * blockDim.x + threadIdx.x) >> 5;
    const int sl = threadIdx.x & 31;
    if (node >= N_NODES) return;
    const int p0 = ptr[node], p1 = ptr[node + 1];
    const int sub = sl >> 4;
    const size_t coff = (size_t)(sl & 15) * 4;
    float c0 = 0.f, c1 = 0.f, c2 = 0.f, c3 = 0.f;
    float d0 = 0.f, d1 = 0.f, d2 = 0.f, d3 = 0.f;
    int p = p0;
    for (; p + 15 < p1; p += 16) {
        int s[8];
#pragma unroll
        for (int k = 0; k < 8; ++k) s[k] = adj[p + 2 * k + sub];
#pragma unroll
        for (int k = 0; k < 8; ++k) {
            uint2 u = *(const uint2*)(feat + (size_t)s[k] * 64 + coff);
            if (k & 1) { d0 += BFLO(u.x); d1 += BFHI(u.x); d2 += BFLO(u.y); d3 += BFHI(u.y); }
            else       { c0 += BFLO(u.x); c1 += BFHI(u.x); c2 += BFLO(u.y); c3 += BFHI(u.y); }
        }
    }
    for (; p + 7 < p1; p += 8) {
        int s[4];
#pragma unroll
        for (int k = 0; k < 4; ++k) s[k] = adj[p + 2 * k + sub];
#pragma unroll
        for (int k = 0; k < 4; ++k) {
            uint2 u = *(const uint2*)(feat + (size_t)s[k] * 64 + coff);
            if (k & 1) { d0 += BFLO(u.x); d1 += BFHI(u.x); d2 += BFLO(u.y); d3 += BFHI(u.y); }
            else       { c0 += BFLO(u.x); c1 += BFHI(u.x); c2 += BFLO(u.y); c3 += BFHI(u.y); }
        }
    }
    for (; p + 1 < p1; p += 2) {
        int s = adj[p + sub];
        uint2 u = *(const uint2*)(feat + (size_t)s * 64 + coff);
        c0 += BFLO(u.x); c1 += BFHI(u.x); c2 += BFLO(u.y); c3 += BFHI(u.y);
    }
    if (p < p1 && sub == 0) {
        int s = adj[p];
        uint2 u = *(const uint2*)(feat + (size_t)s * 64 + coff);
        c0 += BFLO(u.x); c1 += BFHI(u.x); c2 += BFLO(u.y); c3 += BFHI(u.y);
    }
    c0 += d0; c1 += d1; c2 += d2; c3 += d3;
    c0 += __shfl_xor(c0, 16);
    c1 += __shfl_xor(c1, 16);
    c2 += __shfl_xor(c2, 16);
    c3 += __shfl_xor(c3, 16);
    if (sub == 0) {
        const float inv = 1.0f / (float)max(p1 - p0, 1);
        uint2 zu = *(const uint2*)(zb + (size_t)node * 64 + coff);
        float4 o;
        o.x = BFLO(zu.x) + c0 * inv;
        o.y = BFHI(zu.x) + c1 * inv;
        o.z = BFLO(zu.y) + c2 * inv;
        o.w = BFHI(zu.y) + c3 * inv;
        *(float4*)(out + (size_t)node * 64 + coff) = o;
    }
}

// ---------------------------------------------------------------------------
extern "C" void kernel_launch(void* const* d_in, const int* in_sizes, int n_in,
                              void* d_out, int out_size, void* d_ws, size_t ws_size,
                              hipStream_t stream) {
    const float* x   = (const float*)d_in[0];
    const int*   ei  = (const int*)d_in[1];
    const float* W1l = (const float*)d_in[2];
    const float* b1  = (const float*)d_in[3];
    const float* W1r = (const float*)d_in[4];
    const float* W2l = (const float*)d_in[5];
    const float* b2  = (const float*)d_in[6];
    const float* W2r = (const float*)d_in[7];
    float* out = (float*)d_out;

    char* w = (char*)d_ws;
    int* flag   = (int*)w;                       // 64 ints
    int* bincur = flag + 64;                     // 1024 (NBIN used)
    int* ptr    = bincur + 1024;                 // N+1
    int* adj    = ptr + (N_NODES + 1);           // NE
    size_t koff = (((size_t)(64 + 1024 + N_NODES + 1 + NE)) * 4 + 255)
                  & ~(size_t)255;
    unsigned long long* kmask = (unsigned long long*)(w + koff);  // 200000 ull
    size_t foff = (koff + (size_t)NMASKW * 8 + 255) & ~(size_t)255;
    __hip_bfloat16* wb    = (__hip_bfloat16*)(w + foff);        // 49152
    __hip_bfloat16* w1lb  = wb;
    __hip_bfloat16* w1rb  = wb + 16384;
    __hip_bfloat16* w2lb  = wb + 32768;
    __hip_bfloat16* w2rb  = wb + 40960;
    __hip_bfloat16* xb    = wb + 49152;                         // N*128
    __hip_bfloat16* meanb = xb + (size_t)N_NODES * 128;         // N*128
    char* pregion = (char*)(meanb + (size_t)N_NODES * 128);
    int* pairs = (int*)pregion;                      // 9.6 MB, dead after bin2csr
    __hip_bfloat16* y2b = (__hip_bfloat16*)pregion;  // [N,64] overlay (12.8 MB)
    __hip_bfloat16* zbb = y2b + (size_t)N_NODES * 64; // [N,64] bf16 z (12.8 MB)

    k_pre<<<2048, 256, 0, stream>>>((const float4*)x, (ushort4*)xb,
                                    W1l, W1r, W2l, W2r, wb,
                                    ei, flag, bincur, kmask);

    k_binscatter<<<NBLK, 1024, 0, stream>>>(ei, flag, bincur, pairs);
    k_bin2csr<<<NBIN, 256, 0, stream>>>(pairs, bincur, ptr, adj);

    const int ab  = (N_NODES + 3) / 4;           // k_agg:   4 nodes / 256-block
    const int nb  = (N_NODES + 63) / 64;         // k_lin1f: 1563 blocks (64-row)
    const int ab2 = (N_NODES + 7) / 8;           // k_agg2f: 8 nodes / 256-block

    k_agg<<<ab, 256, 0, stream>>>(xb, ptr, adj, meanb);
    k_lin1f<<<nb, 256, 0, stream>>>(meanb, xb, w1lb, w1rb, b1,
                                    w2lb, w2rb, b2, kmask, y2b, zbb);
    k_agg2f<<<ab2, 256, 0, stream>>>(y2b, ptr, adj, zbb, out);
}